// Round 10
// baseline (200.852 us; speedup 1.0000x reference)
//
#include <hip/hip_runtime.h>
#include <hip/hip_fp16.h>
#include <math.h>

#define NN 100000
#define F0 128
#define F1 16
#define F2 10
#define NBUCK 391   // ceil(NN / 256)
#define TILE 8192   // edges per binplace block (32KB stage)
#define EPT 16      // edges per thread in binplace (TILE / BPT)
#define CAP 16384   // LDS staging capacity in k_bucket
#define BPT 512     // binplace threads

__device__ inline void fma4(float4& a, float s, const float4& w) {
  a.x = fmaf(s, w.x, a.x);
  a.y = fmaf(s, w.y, a.y);
  a.z = fmaf(s, w.z, a.z);
  a.w = fmaf(s, w.w, a.w);
}

__device__ inline unsigned pk2(float a, float b) {
  __half ha = __float2half(a), hb = __float2half(b);
  return (unsigned)__half_as_ushort(ha) | ((unsigned)__half_as_ushort(hb) << 16);
}

__device__ inline float2 up2(unsigned u) {
  __half2 h;
  *(unsigned*)&h = u;
  return __half22float2(h);
}

__device__ inline void nt_store_f2(float a, float b, float* p) {
  union { double d; float f[2]; } u;
  u.f[0] = a; u.f[1] = b;
  __builtin_nontemporal_store(u.d, (double*)p);
}

// ==================== CSR build (two-level counting sort) ====================
__global__ void k_zero(int* __restrict__ bucket_cnt) {
  int i = blockIdx.x * blockDim.x + threadIdx.x;
  if (i < NBUCK) bucket_cnt[i] = 0;
}

__global__ __launch_bounds__(256) void k_bincount(const int* __restrict__ dst, int E,
                                                  int* __restrict__ bucket_cnt) {
  __shared__ int hist[NBUCK];
  int t = threadIdx.x;
  for (int i = t; i < NBUCK; i += 256) hist[i] = 0;
  __syncthreads();
  int per = (E + gridDim.x - 1) / gridDim.x;
  int e0 = blockIdx.x * per, e1 = min(E, e0 + per);
  for (int e = e0 + t; e < e1; e += 256)
    atomicAdd(&hist[__builtin_nontemporal_load(dst + e) >> 8], 1);
  __syncthreads();
  for (int i = t; i < NBUCK; i += 256)
    if (hist[i]) atomicAdd(&bucket_cnt[i], hist[i]);
}

__global__ void k_binscan(const int* __restrict__ bucket_cnt, int* __restrict__ bucket_base,
                          int* __restrict__ bucket_cur) {
  __shared__ int lds[512];
  int t = threadIdx.x;
  int v = (t < NBUCK) ? bucket_cnt[t] : 0;
  lds[t] = v;
  __syncthreads();
  for (int o = 1; o < 512; o <<= 1) {
    int add = (t >= o) ? lds[t - o] : 0;
    __syncthreads();
    lds[t] += add;
    __syncthreads();
  }
  if (t < NBUCK) {
    int excl = lds[t] - v;
    bucket_base[t] = excl;
    bucket_cur[t] = excl;
    if (t == NBUCK - 1) bucket_base[NBUCK] = lds[t];  // == E
  }
}

// LDS-reorder binplace with remembered-position scatter.
__global__ __launch_bounds__(BPT) void k_binplace(const int* __restrict__ src,
                                                  const int* __restrict__ dst, int E,
                                                  int* __restrict__ bucket_cur,
                                                  int* __restrict__ packed) {
  __shared__ int cnt[NBUCK];
  __shared__ int loff[NBUCK];
  __shared__ int gbase[NBUCK];
  __shared__ int part[256];
  __shared__ int stage[TILE];
  int t = threadIdx.x;
  int e0 = blockIdx.x * TILE, e1 = min(E, e0 + TILE);
  int total = e1 - e0;
  for (int i = t; i < NBUCK; i += BPT) cnt[i] = 0;
  __syncthreads();
  int bkpos[EPT];
  int pval[EPT];
#pragma unroll
  for (int k = 0; k < EPT; k++) {
    int e = e0 + t + k * BPT;
    if (e < e1) {
      int d = __builtin_nontemporal_load(dst + e);
      int s = __builtin_nontemporal_load(src + e);
      int bk = d >> 8;
      int pos = atomicAdd(&cnt[bk], 1);
      bkpos[k] = (bk << 13) | pos;
      pval[k] = (s << 8) | (d & 255);
    } else {
      bkpos[k] = -1;
    }
  }
  __syncthreads();
  for (int i = t; i < NBUCK; i += BPT) {
    int c = cnt[i];
    gbase[i] = c ? atomicAdd(&bucket_cur[i], c) : 0;
  }
  if (t < 256) {
    int i0 = 2 * t, i1 = 2 * t + 1;
    int c0 = (i0 < NBUCK) ? cnt[i0] : 0;
    int c1 = (i1 < NBUCK) ? cnt[i1] : 0;
    part[t] = c0 + c1;
  }
  __syncthreads();
  for (int o = 1; o < 256; o <<= 1) {
    int add = 0;
    if (t < 256 && t >= o) add = part[t - o];
    __syncthreads();
    if (t < 256) part[t] += add;
    __syncthreads();
  }
  if (t < 256) {
    int i0 = 2 * t, i1 = 2 * t + 1;
    int c0 = (i0 < NBUCK) ? cnt[i0] : 0;
    int c1 = (i1 < NBUCK) ? cnt[i1] : 0;
    int excl = part[t] - c0 - c1;
    if (i0 < NBUCK) loff[i0] = excl;
    if (i1 < NBUCK) loff[i1] = excl + c0;
  }
  __syncthreads();
#pragma unroll
  for (int k = 0; k < EPT; k++) {
    if (bkpos[k] >= 0) {
      int bk = bkpos[k] >> 13, pos = bkpos[k] & 8191;
      stage[loff[bk] + pos] = pval[k];
    }
  }
  __syncthreads();
  int sub = t >> 4, lane = t & 15;
  for (int bk = sub; bk < NBUCK; bk += BPT / 16) {
    int lo = loff[bk];
    int hi = (bk + 1 < NBUCK) ? loff[bk + 1] : total;
    int gb = gbase[bk];
    for (int i = lo + lane; i < hi; i += 16) packed[gb + (i - lo)] = stage[i];
  }
}

__global__ __launch_bounds__(256) void k_bucket(const int* __restrict__ packed,
                                                const int* __restrict__ bucket_base,
                                                int* __restrict__ row_start,
                                                float* __restrict__ dinv,
                                                int* __restrict__ col, int E) {
  __shared__ int stage[CAP];
  __shared__ int hist[256];
  __shared__ int off[256];
  __shared__ int cur[256];
  int b = blockIdx.x, t = threadIdx.x;
  int base = bucket_base[b];
  int cnt = bucket_base[b + 1] - base;
  hist[t] = 0;
  bool staged = (cnt <= CAP);
  if (staged)
    for (int i = t; i < cnt; i += 256) stage[i] = __builtin_nontemporal_load(packed + base + i);
  __syncthreads();
  if (staged) {
    for (int i = t; i < cnt; i += 256) atomicAdd(&hist[stage[i] & 255], 1);
  } else {
    for (int i = t; i < cnt; i += 256) atomicAdd(&hist[packed[base + i] & 255], 1);
  }
  __syncthreads();
  int v = hist[t];
  off[t] = v;
  __syncthreads();
  for (int o = 1; o < 256; o <<= 1) {
    int add = (t >= o) ? off[t - o] : 0;
    __syncthreads();
    off[t] += add;
    __syncthreads();
  }
  int excl = off[t] - v;
  cur[t] = excl;
  int d = b * 256 + t;
  if (d < NN) {
    row_start[d] = base + excl;
    dinv[d] = rsqrtf((float)(v + 1));  // +1 self-loop
  }
  if (b == 0 && t == 0) row_start[NN] = E;
  __syncthreads();
  if (staged) {
    for (int i = t; i < cnt; i += 256) {
      int p = stage[i];
      int pos = atomicAdd(&cur[p & 255], 1);
      col[base + pos] = p >> 8;
    }
  } else {
    for (int i = t; i < cnt; i += 256) {
      int p = packed[base + i];
      int pos = atomicAdd(&cur[p & 255], 1);
      col[base + pos] = p >> 8;
    }
  }
}

// ==================== tab1 = fp16(dinv * (x @ W1)), [N][16] fp16 (3.2 MB) ====================
__global__ __launch_bounds__(256) void k_lin1(const float* __restrict__ x,
                                              const float* __restrict__ W1,
                                              const float* __restrict__ dinv,
                                              unsigned* __restrict__ tab1) {
  __shared__ float4 wl[F0 * 4];  // [k][jq], 8 KB
  int t = threadIdx.x;
  for (int i = t; i < F0 * 4; i += 256) wl[i] = ((const float4*)W1)[i];
  __syncthreads();
  int row0 = (blockIdx.x * 256 + t) * 4;
  if (row0 >= NN) return;  // N % 4 == 0
  float4 acc[4][4];
#pragma unroll
  for (int r = 0; r < 4; r++)
#pragma unroll
    for (int j = 0; j < 4; j++) acc[r][j] = make_float4(0.f, 0.f, 0.f, 0.f);
  const float4* xr0 = (const float4*)(x + (size_t)(row0 + 0) * F0);
  const float4* xr1 = (const float4*)(x + (size_t)(row0 + 1) * F0);
  const float4* xr2 = (const float4*)(x + (size_t)(row0 + 2) * F0);
  const float4* xr3 = (const float4*)(x + (size_t)(row0 + 3) * F0);
  for (int k4 = 0; k4 < F0 / 4; k4++) {
    float4 xv[4];
    xv[0] = xr0[k4]; xv[1] = xr1[k4]; xv[2] = xr2[k4]; xv[3] = xr3[k4];
#pragma unroll
    for (int kk = 0; kk < 4; kk++) {
      float4 w0 = wl[(k4 * 4 + kk) * 4 + 0];
      float4 w1 = wl[(k4 * 4 + kk) * 4 + 1];
      float4 w2 = wl[(k4 * 4 + kk) * 4 + 2];
      float4 w3 = wl[(k4 * 4 + kk) * 4 + 3];
#pragma unroll
      for (int r = 0; r < 4; r++) {
        float xs = kk == 0 ? xv[r].x : kk == 1 ? xv[r].y : kk == 2 ? xv[r].z : xv[r].w;
        fma4(acc[r][0], xs, w0);
        fma4(acc[r][1], xs, w1);
        fma4(acc[r][2], xs, w2);
        fma4(acc[r][3], xs, w3);
      }
    }
  }
#pragma unroll
  for (int r = 0; r < 4; r++) {
    float dd = dinv[row0 + r];
    float4 a0 = acc[r][0], a1 = acc[r][1], a2 = acc[r][2], a3 = acc[r][3];
    uint4 o0, o1;
    o0.x = pk2(dd * a0.x, dd * a0.y);
    o0.y = pk2(dd * a0.z, dd * a0.w);
    o0.z = pk2(dd * a1.x, dd * a1.y);
    o0.w = pk2(dd * a1.z, dd * a1.w);
    o1.x = pk2(dd * a2.x, dd * a2.y);
    o1.y = pk2(dd * a2.z, dd * a2.w);
    o1.z = pk2(dd * a3.x, dd * a3.y);
    o1.w = pk2(dd * a3.z, dd * a3.w);
    uint4* orow = (uint4*)(tab1 + (size_t)(row0 + r) * 8);
    orow[0] = o0;
    orow[1] = o1;
  }
}

// ==================== agg1 (+bias+ReLU) fused with lin2 ====================
// Quad per dst; lanes process the SAME edge, each loading its 8B slice of the 32B row
// (intra-quad coalesced: 4 lanes hit the same 64B line -> ~1 transaction/edge).
__global__ __launch_bounds__(256) void k_agg1(const unsigned* __restrict__ tab1,
                                              const int* __restrict__ row_start,
                                              const int* __restrict__ col,
                                              const float* __restrict__ dinv,
                                              const float* __restrict__ b1,
                                              const float* __restrict__ W2g,
                                              unsigned* __restrict__ tab2) {
  __shared__ float w2[F1][F2];
  __shared__ float b1l[F1];
  int t = threadIdx.x;
  if (t < F1 * F2) w2[t / F2][t % F2] = W2g[t];
  if (t < F1) b1l[t] = b1[t];
  __syncthreads();
  int g = blockIdx.x * 256 + t;
  int d = g >> 2, q = g & 3;
  if (d >= NN) return;
  const uint2* T = (const uint2*)tab1;  // [N][4] slices of 4 fp16
  float a0 = 0.f, a1 = 0.f, a2 = 0.f, a3 = 0.f;
  auto addrow = [&](int s) {
    uint2 v = T[(size_t)s * 4 + q];
    float2 f0 = up2(v.x), f1 = up2(v.y);
    a0 += f0.x; a1 += f0.y; a2 += f1.x; a3 += f1.y;
  };
  addrow(d);  // self-loop (each lane adds its own slice)
  int e = row_start[d], e1 = row_start[d + 1];
  for (; e + 3 < e1; e += 4) {
    int s0 = __builtin_nontemporal_load(col + e);
    int s1 = __builtin_nontemporal_load(col + e + 1);
    int s2 = __builtin_nontemporal_load(col + e + 2);
    int s3 = __builtin_nontemporal_load(col + e + 3);
    addrow(s0); addrow(s1); addrow(s2); addrow(s3);
  }
  for (; e < e1; e++) addrow(__builtin_nontemporal_load(col + e));
  float dd = dinv[d];
  float h[4];
  h[0] = fmaxf(fmaf(dd, a0, b1l[q * 4 + 0]), 0.f);
  h[1] = fmaxf(fmaf(dd, a1, b1l[q * 4 + 1]), 0.f);
  h[2] = fmaxf(fmaf(dd, a2, b1l[q * 4 + 2]), 0.f);
  h[3] = fmaxf(fmaf(dd, a3, b1l[q * 4 + 3]), 0.f);
  float p[F2];
#pragma unroll
  for (int j = 0; j < F2; j++) {
    float s = 0.f;
#pragma unroll
    for (int kk = 0; kk < 4; kk++) s = fmaf(h[kk], w2[q * 4 + kk][j], s);
    p[j] = s;
  }
#pragma unroll
  for (int j = 0; j < F2; j++) p[j] += __shfl_xor(p[j], 1);
#pragma unroll
  for (int j = 0; j < F2; j++) p[j] += __shfl_xor(p[j], 2);
  uint2* O = (uint2*)tab2;  // [N][4] slices
  uint2 o;
  if (q == 0) {
    o.x = pk2(dd * p[0], dd * p[1]); o.y = pk2(dd * p[2], dd * p[3]);
  } else if (q == 1) {
    o.x = pk2(dd * p[4], dd * p[5]); o.y = pk2(dd * p[6], dd * p[7]);
  } else if (q == 2) {
    o.x = pk2(dd * p[8], dd * p[9]); o.y = 0u;
  } else {
    o.x = 0u; o.y = 0u;
  }
  O[(size_t)d * 4 + q] = o;
}

// ==================== agg2 + bias + log_softmax; quad per dst, sliced rows ====================
__global__ __launch_bounds__(256) void k_agg2(const unsigned* __restrict__ tab2,
                                              const int* __restrict__ row_start,
                                              const int* __restrict__ col,
                                              const float* __restrict__ dinv,
                                              const float* __restrict__ b2,
                                              float* __restrict__ out) {
  __shared__ float b2l[F1];  // padded to 16; entries >= F2 are -1e30 (masked in max & sum)
  int t = threadIdx.x;
  if (t < F1) b2l[t] = (t < F2) ? b2[t] : -1e30f;
  __syncthreads();
  int g = blockIdx.x * 256 + t;
  int d = g >> 2, q = g & 3;
  if (d >= NN) return;
  const uint2* T = (const uint2*)tab2;
  float a0 = 0.f, a1 = 0.f, a2 = 0.f, a3 = 0.f;
  auto addrow = [&](int s) {
    uint2 v = T[(size_t)s * 4 + q];
    float2 f0 = up2(v.x), f1 = up2(v.y);
    a0 += f0.x; a1 += f0.y; a2 += f1.x; a3 += f1.y;
  };
  addrow(d);  // self-loop
  int e = row_start[d], e1 = row_start[d + 1];
  for (; e + 3 < e1; e += 4) {
    int s0 = __builtin_nontemporal_load(col + e);
    int s1 = __builtin_nontemporal_load(col + e + 1);
    int s2 = __builtin_nontemporal_load(col + e + 2);
    int s3 = __builtin_nontemporal_load(col + e + 3);
    addrow(s0); addrow(s1); addrow(s2); addrow(s3);
  }
  for (; e < e1; e++) addrow(__builtin_nontemporal_load(col + e));
  float dd = dinv[d];
  float v0 = fmaf(dd, a0, b2l[q * 4 + 0]);
  float v1 = fmaf(dd, a1, b2l[q * 4 + 1]);
  float v2 = fmaf(dd, a2, b2l[q * 4 + 2]);
  float v3 = fmaf(dd, a3, b2l[q * 4 + 3]);
  float m = fmaxf(fmaxf(v0, v1), fmaxf(v2, v3));
  m = fmaxf(m, __shfl_xor(m, 1));
  m = fmaxf(m, __shfl_xor(m, 2));
  float sum = expf(v0 - m) + expf(v1 - m) + expf(v2 - m) + expf(v3 - m);
  sum += __shfl_xor(sum, 1);
  sum += __shfl_xor(sum, 2);
  float lse = m + logf(sum);
  float* o = out + (size_t)d * F2;
  if (q == 0) {
    nt_store_f2(v0 - lse, v1 - lse, o + 0);
    nt_store_f2(v2 - lse, v3 - lse, o + 2);
  } else if (q == 1) {
    nt_store_f2(v0 - lse, v1 - lse, o + 4);
    nt_store_f2(v2 - lse, v3 - lse, o + 6);
  } else if (q == 2) {
    nt_store_f2(v0 - lse, v1 - lse, o + 8);
  }
}

extern "C" void kernel_launch(void* const* d_in, const int* in_sizes, int n_in,
                              void* d_out, int out_size, void* d_ws, size_t ws_size,
                              hipStream_t stream) {
  const float* x  = (const float*)d_in[0];
  const int*   ei = (const int*)d_in[1];
  const float* W1 = (const float*)d_in[2];
  const float* b1 = (const float*)d_in[3];
  const float* W2 = (const float*)d_in[4];
  const float* b2 = (const float*)d_in[5];
  float* out = (float*)d_out;
  int E = in_sizes[1] / 2;
  const int* src = ei;
  const int* dst = ei + E;

  char* p = (char*)d_ws;
  auto alloc = [&](size_t bytes) {
    char* r = p;
    p += (bytes + 255) & ~(size_t)255;
    return r;
  };
  size_t tabsz = (size_t)NN * 8 * 4;  // 3.2 MB ([N][16] fp16 = [N][8] uints)
  float* dinv        = (float*)alloc((size_t)NN * 4);
  int*   row_start   = (int*)alloc((size_t)(NN + 1) * 4);
  int*   bucket_cnt  = (int*)alloc((size_t)NBUCK * 4);
  int*   bucket_base = (int*)alloc((size_t)(NBUCK + 1) * 4);
  int*   bucket_cur  = (int*)alloc((size_t)NBUCK * 4);
  int*   col         = (int*)alloc((size_t)E * 4);
  size_t needA = tabsz * 2;
  size_t regA = (size_t)E * 4;
  char*  A = (char*)alloc(regA > needA ? regA : needA);
  int*      packed = (int*)A;
  unsigned* tab1 = (unsigned*)A;
  unsigned* tab2 = (unsigned*)(A + tabsz);

  int nblk4N = (4 * NN + 255) / 256;    // 1563
  int nblk_place = (E + TILE - 1) / TILE;
  hipLaunchKernelGGL(k_zero, dim3(2), dim3(256), 0, stream, bucket_cnt);
  hipLaunchKernelGGL(k_bincount, dim3(1024), dim3(256), 0, stream, dst, E, bucket_cnt);
  hipLaunchKernelGGL(k_binscan, dim3(1), dim3(512), 0, stream, bucket_cnt, bucket_base, bucket_cur);
  hipLaunchKernelGGL(k_binplace, dim3(nblk_place), dim3(BPT), 0, stream, src, dst, E, bucket_cur, packed);
  hipLaunchKernelGGL(k_bucket, dim3(NBUCK), dim3(256), 0, stream, packed, bucket_base, row_start, dinv, col, E);
  hipLaunchKernelGGL(k_lin1, dim3((NN / 4 + 255) / 256), dim3(256), 0, stream, x, W1, dinv, tab1);
  hipLaunchKernelGGL(k_agg1, dim3(nblk4N), dim3(256), 0, stream,
                     tab1, row_start, col, dinv, b1, W2, tab2);
  hipLaunchKernelGGL(k_agg2, dim3(nblk4N), dim3(256), 0, stream, tab2, row_start, col, dinv, b2, out);
}

// Round 11
// 197.653 us; speedup vs baseline: 1.0162x; 1.0162x over previous
//
#include <hip/hip_runtime.h>
#include <hip/hip_fp16.h>
#include <math.h>

#define NN 100000
#define F0 128
#define F1 16
#define F2 10
#define NBUCK 391   // ceil(NN / 256)
#define TILE 8192   // edges per binplace block (32KB stage)
#define EPT 16      // edges per thread in binplace (TILE / BPT)
#define CAP 16384   // LDS staging capacity in k_bucket
#define BPT 512     // binplace threads

__device__ inline void fma4(float4& a, float s, const float4& w) {
  a.x = fmaf(s, w.x, a.x);
  a.y = fmaf(s, w.y, a.y);
  a.z = fmaf(s, w.z, a.z);
  a.w = fmaf(s, w.w, a.w);
}

__device__ inline unsigned pk2(float a, float b) {
  __half ha = __float2half(a), hb = __float2half(b);
  return (unsigned)__half_as_ushort(ha) | ((unsigned)__half_as_ushort(hb) << 16);
}

__device__ inline float2 up2(unsigned u) {
  __half2 h;
  *(unsigned*)&h = u;
  return __half22float2(h);
}

__device__ inline void nt_store_f2(float a, float b, float* p) {
  union { double d; float f[2]; } u;
  u.f[0] = a; u.f[1] = b;
  __builtin_nontemporal_store(u.d, (double*)p);
}

// ==================== CSR build (two-level counting sort) ====================
__global__ void k_zero(int* __restrict__ bucket_cnt) {
  int i = blockIdx.x * blockDim.x + threadIdx.x;
  if (i < NBUCK) bucket_cnt[i] = 0;
}

__global__ __launch_bounds__(256) void k_bincount(const int* __restrict__ dst, int E,
                                                  int* __restrict__ bucket_cnt) {
  __shared__ int hist[NBUCK];
  int t = threadIdx.x;
  for (int i = t; i < NBUCK; i += 256) hist[i] = 0;
  __syncthreads();
  int per = (E + gridDim.x - 1) / gridDim.x;
  int e0 = blockIdx.x * per, e1 = min(E, e0 + per);
  for (int e = e0 + t; e < e1; e += 256)
    atomicAdd(&hist[__builtin_nontemporal_load(dst + e) >> 8], 1);
  __syncthreads();
  for (int i = t; i < NBUCK; i += 256)
    if (hist[i]) atomicAdd(&bucket_cnt[i], hist[i]);
}

__global__ void k_binscan(const int* __restrict__ bucket_cnt, int* __restrict__ bucket_base,
                          int* __restrict__ bucket_cur) {
  __shared__ int lds[512];
  int t = threadIdx.x;
  int v = (t < NBUCK) ? bucket_cnt[t] : 0;
  lds[t] = v;
  __syncthreads();
  for (int o = 1; o < 512; o <<= 1) {
    int add = (t >= o) ? lds[t - o] : 0;
    __syncthreads();
    lds[t] += add;
    __syncthreads();
  }
  if (t < NBUCK) {
    int excl = lds[t] - v;
    bucket_base[t] = excl;
    bucket_cur[t] = excl;
    if (t == NBUCK - 1) bucket_base[NBUCK] = lds[t];  // == E
  }
}

// LDS-reorder binplace with remembered-position scatter.
__global__ __launch_bounds__(BPT) void k_binplace(const int* __restrict__ src,
                                                  const int* __restrict__ dst, int E,
                                                  int* __restrict__ bucket_cur,
                                                  int* __restrict__ packed) {
  __shared__ int cnt[NBUCK];
  __shared__ int loff[NBUCK];
  __shared__ int gbase[NBUCK];
  __shared__ int part[256];
  __shared__ int stage[TILE];
  int t = threadIdx.x;
  int e0 = blockIdx.x * TILE, e1 = min(E, e0 + TILE);
  int total = e1 - e0;
  for (int i = t; i < NBUCK; i += BPT) cnt[i] = 0;
  __syncthreads();
  int bkpos[EPT];
  int pval[EPT];
#pragma unroll
  for (int k = 0; k < EPT; k++) {
    int e = e0 + t + k * BPT;
    if (e < e1) {
      int d = __builtin_nontemporal_load(dst + e);
      int s = __builtin_nontemporal_load(src + e);
      int bk = d >> 8;
      int pos = atomicAdd(&cnt[bk], 1);
      bkpos[k] = (bk << 13) | pos;
      pval[k] = (s << 8) | (d & 255);
    } else {
      bkpos[k] = -1;
    }
  }
  __syncthreads();
  for (int i = t; i < NBUCK; i += BPT) {
    int c = cnt[i];
    gbase[i] = c ? atomicAdd(&bucket_cur[i], c) : 0;
  }
  if (t < 256) {
    int i0 = 2 * t, i1 = 2 * t + 1;
    int c0 = (i0 < NBUCK) ? cnt[i0] : 0;
    int c1 = (i1 < NBUCK) ? cnt[i1] : 0;
    part[t] = c0 + c1;
  }
  __syncthreads();
  for (int o = 1; o < 256; o <<= 1) {
    int add = 0;
    if (t < 256 && t >= o) add = part[t - o];
    __syncthreads();
    if (t < 256) part[t] += add;
    __syncthreads();
  }
  if (t < 256) {
    int i0 = 2 * t, i1 = 2 * t + 1;
    int c0 = (i0 < NBUCK) ? cnt[i0] : 0;
    int c1 = (i1 < NBUCK) ? cnt[i1] : 0;
    int excl = part[t] - c0 - c1;
    if (i0 < NBUCK) loff[i0] = excl;
    if (i1 < NBUCK) loff[i1] = excl + c0;
  }
  __syncthreads();
#pragma unroll
  for (int k = 0; k < EPT; k++) {
    if (bkpos[k] >= 0) {
      int bk = bkpos[k] >> 13, pos = bkpos[k] & 8191;
      stage[loff[bk] + pos] = pval[k];
    }
  }
  __syncthreads();
  int sub = t >> 4, lane = t & 15;
  for (int bk = sub; bk < NBUCK; bk += BPT / 16) {
    int lo = loff[bk];
    int hi = (bk + 1 < NBUCK) ? loff[bk + 1] : total;
    int gb = gbase[bk];
    for (int i = lo + lane; i < hi; i += 16) packed[gb + (i - lo)] = stage[i];
  }
}

__global__ __launch_bounds__(256) void k_bucket(const int* __restrict__ packed,
                                                const int* __restrict__ bucket_base,
                                                int* __restrict__ row_start,
                                                float* __restrict__ dinv,
                                                int* __restrict__ col, int E) {
  __shared__ int stage[CAP];
  __shared__ int hist[256];
  __shared__ int off[256];
  __shared__ int cur[256];
  int b = blockIdx.x, t = threadIdx.x;
  int base = bucket_base[b];
  int cnt = bucket_base[b + 1] - base;
  hist[t] = 0;
  bool staged = (cnt <= CAP);
  if (staged)
    for (int i = t; i < cnt; i += 256) stage[i] = __builtin_nontemporal_load(packed + base + i);
  __syncthreads();
  if (staged) {
    for (int i = t; i < cnt; i += 256) atomicAdd(&hist[stage[i] & 255], 1);
  } else {
    for (int i = t; i < cnt; i += 256) atomicAdd(&hist[packed[base + i] & 255], 1);
  }
  __syncthreads();
  int v = hist[t];
  off[t] = v;
  __syncthreads();
  for (int o = 1; o < 256; o <<= 1) {
    int add = (t >= o) ? off[t - o] : 0;
    __syncthreads();
    off[t] += add;
    __syncthreads();
  }
  int excl = off[t] - v;
  cur[t] = excl;
  int d = b * 256 + t;
  if (d < NN) {
    row_start[d] = base + excl;
    dinv[d] = rsqrtf((float)(v + 1));  // +1 self-loop
  }
  if (b == 0 && t == 0) row_start[NN] = E;
  __syncthreads();
  if (staged) {
    for (int i = t; i < cnt; i += 256) {
      int p = stage[i];
      int pos = atomicAdd(&cur[p & 255], 1);
      col[base + pos] = p >> 8;
    }
  } else {
    for (int i = t; i < cnt; i += 256) {
      int p = packed[base + i];
      int pos = atomicAdd(&cur[p & 255], 1);
      col[base + pos] = p >> 8;
    }
  }
}

// ==================== tab1 = fp16(dinv * (x @ W1)), [N][16] fp16 (3.2 MB) ====================
__global__ __launch_bounds__(256) void k_lin1(const float* __restrict__ x,
                                              const float* __restrict__ W1,
                                              const float* __restrict__ dinv,
                                              unsigned* __restrict__ tab1) {
  __shared__ float4 wl[F0 * 4];  // [k][jq], 8 KB
  int t = threadIdx.x;
  for (int i = t; i < F0 * 4; i += 256) wl[i] = ((const float4*)W1)[i];
  __syncthreads();
  int row0 = (blockIdx.x * 256 + t) * 4;
  if (row0 >= NN) return;  // N % 4 == 0
  float4 acc[4][4];
#pragma unroll
  for (int r = 0; r < 4; r++)
#pragma unroll
    for (int j = 0; j < 4; j++) acc[r][j] = make_float4(0.f, 0.f, 0.f, 0.f);
  const float4* xr0 = (const float4*)(x + (size_t)(row0 + 0) * F0);
  const float4* xr1 = (const float4*)(x + (size_t)(row0 + 1) * F0);
  const float4* xr2 = (const float4*)(x + (size_t)(row0 + 2) * F0);
  const float4* xr3 = (const float4*)(x + (size_t)(row0 + 3) * F0);
  for (int k4 = 0; k4 < F0 / 4; k4++) {
    float4 xv[4];
    xv[0] = xr0[k4]; xv[1] = xr1[k4]; xv[2] = xr2[k4]; xv[3] = xr3[k4];
#pragma unroll
    for (int kk = 0; kk < 4; kk++) {
      float4 w0 = wl[(k4 * 4 + kk) * 4 + 0];
      float4 w1 = wl[(k4 * 4 + kk) * 4 + 1];
      float4 w2 = wl[(k4 * 4 + kk) * 4 + 2];
      float4 w3 = wl[(k4 * 4 + kk) * 4 + 3];
#pragma unroll
      for (int r = 0; r < 4; r++) {
        float xs = kk == 0 ? xv[r].x : kk == 1 ? xv[r].y : kk == 2 ? xv[r].z : xv[r].w;
        fma4(acc[r][0], xs, w0);
        fma4(acc[r][1], xs, w1);
        fma4(acc[r][2], xs, w2);
        fma4(acc[r][3], xs, w3);
      }
    }
  }
#pragma unroll
  for (int r = 0; r < 4; r++) {
    float dd = dinv[row0 + r];
    float4 a0 = acc[r][0], a1 = acc[r][1], a2 = acc[r][2], a3 = acc[r][3];
    uint4 o0, o1;
    o0.x = pk2(dd * a0.x, dd * a0.y);
    o0.y = pk2(dd * a0.z, dd * a0.w);
    o0.z = pk2(dd * a1.x, dd * a1.y);
    o0.w = pk2(dd * a1.z, dd * a1.w);
    o1.x = pk2(dd * a2.x, dd * a2.y);
    o1.y = pk2(dd * a2.z, dd * a2.w);
    o1.z = pk2(dd * a3.x, dd * a3.y);
    o1.w = pk2(dd * a3.z, dd * a3.w);
    uint4* orow = (uint4*)(tab1 + (size_t)(row0 + r) * 8);
    orow[0] = o0;
    orow[1] = o1;
  }
}

// ==================== agg1 (+bias+ReLU) fused with lin2 ====================
// 8 lanes (2 quads) per dst: quad-half q2 takes every other edge (halves the serial
// chain, doubles waves: grid 3125 blocks -> full occupancy); lane slice q keeps the
// intra-quad 64B-line coalescing. shfl_xor(4) merges the halves after the loop.
__global__ __launch_bounds__(256) void k_agg1(const unsigned* __restrict__ tab1,
                                              const int* __restrict__ row_start,
                                              const int* __restrict__ col,
                                              const float* __restrict__ dinv,
                                              const float* __restrict__ b1,
                                              const float* __restrict__ W2g,
                                              unsigned* __restrict__ tab2) {
  __shared__ float w2[F1][F2];
  __shared__ float b1l[F1];
  int t = threadIdx.x;
  if (t < F1 * F2) w2[t / F2][t % F2] = W2g[t];
  if (t < F1) b1l[t] = b1[t];
  __syncthreads();
  int g = blockIdx.x * 256 + t;
  int d = g >> 3, o = g & 7;
  int q2 = o >> 2, q = o & 3;
  if (d >= NN) return;
  const uint2* T = (const uint2*)tab1;  // [N][4] slices of 4 fp16
  float a0 = 0.f, a1 = 0.f, a2 = 0.f, a3 = 0.f;
  auto addrow = [&](int s) {
    uint2 v = T[(size_t)s * 4 + q];
    float2 f0 = up2(v.x), f1 = up2(v.y);
    a0 += f0.x; a1 += f0.y; a2 += f1.x; a3 += f1.y;
  };
  if (q2 == 0) addrow(d);  // self-loop
  int e = row_start[d] + q2, e1 = row_start[d + 1];
  for (; e + 6 < e1; e += 8) {
    int s0 = __builtin_nontemporal_load(col + e);
    int s1 = __builtin_nontemporal_load(col + e + 2);
    int s2 = __builtin_nontemporal_load(col + e + 4);
    int s3 = __builtin_nontemporal_load(col + e + 6);
    addrow(s0); addrow(s1); addrow(s2); addrow(s3);
  }
  for (; e < e1; e += 2) addrow(__builtin_nontemporal_load(col + e));
  // merge the two edge halves
  a0 += __shfl_xor(a0, 4);
  a1 += __shfl_xor(a1, 4);
  a2 += __shfl_xor(a2, 4);
  a3 += __shfl_xor(a3, 4);
  float dd = dinv[d];
  float h[4];
  h[0] = fmaxf(fmaf(dd, a0, b1l[q * 4 + 0]), 0.f);
  h[1] = fmaxf(fmaf(dd, a1, b1l[q * 4 + 1]), 0.f);
  h[2] = fmaxf(fmaf(dd, a2, b1l[q * 4 + 2]), 0.f);
  h[3] = fmaxf(fmaf(dd, a3, b1l[q * 4 + 3]), 0.f);
  float p[F2];
#pragma unroll
  for (int j = 0; j < F2; j++) {
    float s = 0.f;
#pragma unroll
    for (int kk = 0; kk < 4; kk++) s = fmaf(h[kk], w2[q * 4 + kk][j], s);
    p[j] = s;
  }
#pragma unroll
  for (int j = 0; j < F2; j++) p[j] += __shfl_xor(p[j], 1);
#pragma unroll
  for (int j = 0; j < F2; j++) p[j] += __shfl_xor(p[j], 2);
  if (q2 != 0) return;  // duplicate quad
  uint2* O = (uint2*)tab2;  // [N][4] slices
  uint2 ov;
  if (q == 0) {
    ov.x = pk2(dd * p[0], dd * p[1]); ov.y = pk2(dd * p[2], dd * p[3]);
  } else if (q == 1) {
    ov.x = pk2(dd * p[4], dd * p[5]); ov.y = pk2(dd * p[6], dd * p[7]);
  } else if (q == 2) {
    ov.x = pk2(dd * p[8], dd * p[9]); ov.y = 0u;
  } else {
    ov.x = 0u; ov.y = 0u;
  }
  O[(size_t)d * 4 + q] = ov;
}

// ==================== agg2 + bias + log_softmax; 8 lanes per dst ====================
__global__ __launch_bounds__(256) void k_agg2(const unsigned* __restrict__ tab2,
                                              const int* __restrict__ row_start,
                                              const int* __restrict__ col,
                                              const float* __restrict__ dinv,
                                              const float* __restrict__ b2,
                                              float* __restrict__ out) {
  __shared__ float b2l[F1];  // padded to 16; entries >= F2 are -1e30 (masked in max & sum)
  int t = threadIdx.x;
  if (t < F1) b2l[t] = (t < F2) ? b2[t] : -1e30f;
  __syncthreads();
  int g = blockIdx.x * 256 + t;
  int d = g >> 3, o = g & 7;
  int q2 = o >> 2, q = o & 3;
  if (d >= NN) return;
  const uint2* T = (const uint2*)tab2;
  float a0 = 0.f, a1 = 0.f, a2 = 0.f, a3 = 0.f;
  auto addrow = [&](int s) {
    uint2 v = T[(size_t)s * 4 + q];
    float2 f0 = up2(v.x), f1 = up2(v.y);
    a0 += f0.x; a1 += f0.y; a2 += f1.x; a3 += f1.y;
  };
  if (q2 == 0) addrow(d);  // self-loop
  int e = row_start[d] + q2, e1 = row_start[d + 1];
  for (; e + 6 < e1; e += 8) {
    int s0 = __builtin_nontemporal_load(col + e);
    int s1 = __builtin_nontemporal_load(col + e + 2);
    int s2 = __builtin_nontemporal_load(col + e + 4);
    int s3 = __builtin_nontemporal_load(col + e + 6);
    addrow(s0); addrow(s1); addrow(s2); addrow(s3);
  }
  for (; e < e1; e += 2) addrow(__builtin_nontemporal_load(col + e));
  a0 += __shfl_xor(a0, 4);
  a1 += __shfl_xor(a1, 4);
  a2 += __shfl_xor(a2, 4);
  a3 += __shfl_xor(a3, 4);
  float dd = dinv[d];
  float v0 = fmaf(dd, a0, b2l[q * 4 + 0]);
  float v1 = fmaf(dd, a1, b2l[q * 4 + 1]);
  float v2 = fmaf(dd, a2, b2l[q * 4 + 2]);
  float v3 = fmaf(dd, a3, b2l[q * 4 + 3]);
  float m = fmaxf(fmaxf(v0, v1), fmaxf(v2, v3));
  m = fmaxf(m, __shfl_xor(m, 1));
  m = fmaxf(m, __shfl_xor(m, 2));
  float sum = expf(v0 - m) + expf(v1 - m) + expf(v2 - m) + expf(v3 - m);
  sum += __shfl_xor(sum, 1);
  sum += __shfl_xor(sum, 2);
  float lse = m + logf(sum);
  if (q2 != 0) return;  // duplicate quad
  float* op = out + (size_t)d * F2;
  if (q == 0) {
    nt_store_f2(v0 - lse, v1 - lse, op + 0);
    nt_store_f2(v2 - lse, v3 - lse, op + 2);
  } else if (q == 1) {
    nt_store_f2(v0 - lse, v1 - lse, op + 4);
    nt_store_f2(v2 - lse, v3 - lse, op + 6);
  } else if (q == 2) {
    nt_store_f2(v0 - lse, v1 - lse, op + 8);
  }
}

extern "C" void kernel_launch(void* const* d_in, const int* in_sizes, int n_in,
                              void* d_out, int out_size, void* d_ws, size_t ws_size,
                              hipStream_t stream) {
  const float* x  = (const float*)d_in[0];
  const int*   ei = (const int*)d_in[1];
  const float* W1 = (const float*)d_in[2];
  const float* b1 = (const float*)d_in[3];
  const float* W2 = (const float*)d_in[4];
  const float* b2 = (const float*)d_in[5];
  float* out = (float*)d_out;
  int E = in_sizes[1] / 2;
  const int* src = ei;
  const int* dst = ei + E;

  char* p = (char*)d_ws;
  auto alloc = [&](size_t bytes) {
    char* r = p;
    p += (bytes + 255) & ~(size_t)255;
    return r;
  };
  size_t tabsz = (size_t)NN * 8 * 4;  // 3.2 MB ([N][16] fp16 = [N][8] uints)
  float* dinv        = (float*)alloc((size_t)NN * 4);
  int*   row_start   = (int*)alloc((size_t)(NN + 1) * 4);
  int*   bucket_cnt  = (int*)alloc((size_t)NBUCK * 4);
  int*   bucket_base = (int*)alloc((size_t)(NBUCK + 1) * 4);
  int*   bucket_cur  = (int*)alloc((size_t)NBUCK * 4);
  int*   col         = (int*)alloc((size_t)E * 4);
  size_t needA = tabsz * 2;
  size_t regA = (size_t)E * 4;
  char*  A = (char*)alloc(regA > needA ? regA : needA);
  int*      packed = (int*)A;
  unsigned* tab1 = (unsigned*)A;
  unsigned* tab2 = (unsigned*)(A + tabsz);

  int nblk8N = (8 * NN + 255) / 256;    // 3125
  int nblk_place = (E + TILE - 1) / TILE;
  hipLaunchKernelGGL(k_zero, dim3(2), dim3(256), 0, stream, bucket_cnt);
  hipLaunchKernelGGL(k_bincount, dim3(1024), dim3(256), 0, stream, dst, E, bucket_cnt);
  hipLaunchKernelGGL(k_binscan, dim3(1), dim3(512), 0, stream, bucket_cnt, bucket_base, bucket_cur);
  hipLaunchKernelGGL(k_binplace, dim3(nblk_place), dim3(BPT), 0, stream, src, dst, E, bucket_cur, packed);
  hipLaunchKernelGGL(k_bucket, dim3(NBUCK), dim3(256), 0, stream, packed, bucket_base, row_start, dinv, col, E);
  hipLaunchKernelGGL(k_lin1, dim3((NN / 4 + 255) / 256), dim3(256), 0, stream, x, W1, dinv, tab1);
  hipLaunchKernelGGL(k_agg1, dim3(nblk8N), dim3(256), 0, stream,
                     tab1, row_start, col, dinv, b1, W2, tab2);
  hipLaunchKernelGGL(k_agg2, dim3(nblk8N), dim3(256), 0, stream, tab2, row_start, col, dinv, b2, out);
}

// Round 12
// 171.738 us; speedup vs baseline: 1.1695x; 1.1509x over previous
//
#include <hip/hip_runtime.h>
#include <hip/hip_fp16.h>
#include <math.h>

#define NN 100000
#define F0 128
#define F1 16
#define F2 10
#define NBUCK 391    // ceil(NN / 256); bucket b covers dsts [b*256, b*256+255]
#define MAXB 10240   // fixed per-bucket capacity (mean 8184, sigma~90 -> 22 sigma slack)
#define TILE 8192    // edges per binplace block
#define EPT 16       // edges per thread in binplace (TILE / BPT)
#define CAP 10240    // LDS staging capacity in k_bucket (== MAXB)
#define BPT 512      // binplace threads

__device__ inline void fma4(float4& a, float s, const float4& w) {
  a.x = fmaf(s, w.x, a.x);
  a.y = fmaf(s, w.y, a.y);
  a.z = fmaf(s, w.z, a.z);
  a.w = fmaf(s, w.w, a.w);
}

__device__ inline unsigned pk2(float a, float b) {
  __half ha = __float2half(a), hb = __float2half(b);
  return (unsigned)__half_as_ushort(ha) | ((unsigned)__half_as_ushort(hb) << 16);
}

__device__ inline float2 up2(unsigned u) {
  __half2 h;
  *(unsigned*)&h = u;
  return __half22float2(h);
}

__device__ inline void nt_store_f2(float a, float b, float* p) {
  union { double d; float f[2]; } u;
  u.f[0] = a; u.f[1] = b;
  __builtin_nontemporal_store(u.d, (double*)p);
}

// ==================== CSR build ====================
__global__ void k_zero(int* __restrict__ bucket_cur) {
  int i = blockIdx.x * blockDim.x + threadIdx.x;
  if (i < NBUCK) bucket_cur[i] = 0;
}

// LDS-reorder binplace with remembered-position scatter into fixed-capacity buckets.
__global__ __launch_bounds__(BPT) void k_binplace(const int* __restrict__ src,
                                                  const int* __restrict__ dst, int E,
                                                  int* __restrict__ bucket_cur,
                                                  int* __restrict__ packed) {
  __shared__ int cnt[NBUCK];
  __shared__ int loff[NBUCK];
  __shared__ int gbase[NBUCK];
  __shared__ int part[256];
  __shared__ int stage[TILE];
  int t = threadIdx.x;
  int e0 = blockIdx.x * TILE, e1 = min(E, e0 + TILE);
  int total = e1 - e0;
  for (int i = t; i < NBUCK; i += BPT) cnt[i] = 0;
  __syncthreads();
  // phase A: histogram with remembered positions (pos < 8192 -> 13 bits)
  int bkpos[EPT];
  int pval[EPT];
#pragma unroll
  for (int k = 0; k < EPT; k++) {
    int e = e0 + t + k * BPT;
    if (e < e1) {
      int d = __builtin_nontemporal_load(dst + e);
      int s = __builtin_nontemporal_load(src + e);
      int bk = d >> 8;
      int pos = atomicAdd(&cnt[bk], 1);
      bkpos[k] = (bk << 13) | pos;
      pval[k] = (s << 8) | (d & 255);
    } else {
      bkpos[k] = -1;
    }
  }
  __syncthreads();
  // reserve space in fixed-capacity bucket regions
  for (int i = t; i < NBUCK; i += BPT) {
    int c = cnt[i];
    gbase[i] = c ? atomicAdd(&bucket_cur[i], c) : 0;
  }
  // block scan of cnt -> loff
  if (t < 256) {
    int i0 = 2 * t, i1 = 2 * t + 1;
    int c0 = (i0 < NBUCK) ? cnt[i0] : 0;
    int c1 = (i1 < NBUCK) ? cnt[i1] : 0;
    part[t] = c0 + c1;
  }
  __syncthreads();
  for (int o = 1; o < 256; o <<= 1) {
    int add = 0;
    if (t < 256 && t >= o) add = part[t - o];
    __syncthreads();
    if (t < 256) part[t] += add;
    __syncthreads();
  }
  if (t < 256) {
    int i0 = 2 * t, i1 = 2 * t + 1;
    int c0 = (i0 < NBUCK) ? cnt[i0] : 0;
    int c1 = (i1 < NBUCK) ? cnt[i1] : 0;
    int excl = part[t] - c0 - c1;
    if (i0 < NBUCK) loff[i0] = excl;
    if (i1 < NBUCK) loff[i1] = excl + c0;
  }
  __syncthreads();
  // phase B: atomic-free LDS scatter
#pragma unroll
  for (int k = 0; k < EPT; k++) {
    if (bkpos[k] >= 0) {
      int bk = bkpos[k] >> 13, pos = bkpos[k] & 8191;
      stage[loff[bk] + pos] = pval[k];
    }
  }
  __syncthreads();
  // contiguous run copy into padded bucket regions
  int sub = t >> 4, lane = t & 15;
  for (int bk = sub; bk < NBUCK; bk += BPT / 16) {
    int lo = loff[bk];
    int hi = (bk + 1 < NBUCK) ? loff[bk + 1] : total;
    size_t gb = (size_t)bk * MAXB + gbase[bk];
    for (int i = lo + lane; i < hi; i += 16) packed[gb + (i - lo)] = stage[i];
  }
}

// fine pass: remembered-position histogram (1 LDS atomic/edge), scan, atomic-free col write.
__global__ __launch_bounds__(256) void k_bucket(const int* __restrict__ packed,
                                                const int* __restrict__ bucket_cur,
                                                int* __restrict__ row_start,
                                                int* __restrict__ row_end,
                                                float* __restrict__ dinv,
                                                int* __restrict__ col) {
  __shared__ int stage[CAP];
  __shared__ unsigned short posa[CAP];
  __shared__ int hist[256];
  __shared__ int offx[256];
  __shared__ int scan[256];
  __shared__ int cur[256];
  int b = blockIdx.x, t = threadIdx.x;
  size_t base = (size_t)b * MAXB;
  int cnt_b = bucket_cur[b];
  hist[t] = 0;
  __syncthreads();
  bool staged = (cnt_b <= CAP);  // always true in practice (22-sigma margin)
  if (staged) {
    for (int i = t; i < cnt_b; i += 256) {
      int p = __builtin_nontemporal_load(packed + base + i);
      stage[i] = p;
      int pos = atomicAdd(&hist[p & 255], 1);
      posa[i] = (unsigned short)pos;
    }
  } else {
    for (int i = t; i < cnt_b; i += 256)
      atomicAdd(&hist[packed[base + i] & 255], 1);
  }
  __syncthreads();
  int v = hist[t];
  scan[t] = v;
  __syncthreads();
  for (int o = 1; o < 256; o <<= 1) {
    int add = (t >= o) ? scan[t - o] : 0;
    __syncthreads();
    scan[t] += add;
    __syncthreads();
  }
  int excl = scan[t] - v;
  offx[t] = excl;
  cur[t] = excl;
  int d = b * 256 + t;
  if (d < NN) {
    row_start[d] = (int)base + excl;
    row_end[d] = (int)base + excl + v;
    dinv[d] = rsqrtf((float)(v + 1));  // +1 self-loop
  }
  __syncthreads();
  if (staged) {
    for (int i = t; i < cnt_b; i += 256) {
      int p = stage[i];
      col[base + offx[p & 255] + posa[i]] = p >> 8;
    }
  } else {
    for (int i = t; i < cnt_b; i += 256) {
      int p = packed[base + i];
      int pos = atomicAdd(&cur[p & 255], 1);
      col[base + pos] = p >> 8;
    }
  }
}

// ==================== tab1 = fp16(dinv * (x @ W1)), [N][16] fp16 (3.2 MB) ====================
__global__ __launch_bounds__(256) void k_lin1(const float* __restrict__ x,
                                              const float* __restrict__ W1,
                                              const float* __restrict__ dinv,
                                              unsigned* __restrict__ tab1) {
  __shared__ float4 wl[F0 * 4];  // [k][jq], 8 KB
  int t = threadIdx.x;
  for (int i = t; i < F0 * 4; i += 256) wl[i] = ((const float4*)W1)[i];
  __syncthreads();
  int row0 = (blockIdx.x * 256 + t) * 4;
  if (row0 >= NN) return;  // N % 4 == 0
  float4 acc[4][4];
#pragma unroll
  for (int r = 0; r < 4; r++)
#pragma unroll
    for (int j = 0; j < 4; j++) acc[r][j] = make_float4(0.f, 0.f, 0.f, 0.f);
  const float4* xr0 = (const float4*)(x + (size_t)(row0 + 0) * F0);
  const float4* xr1 = (const float4*)(x + (size_t)(row0 + 1) * F0);
  const float4* xr2 = (const float4*)(x + (size_t)(row0 + 2) * F0);
  const float4* xr3 = (const float4*)(x + (size_t)(row0 + 3) * F0);
  for (int k4 = 0; k4 < F0 / 4; k4++) {
    float4 xv[4];
    xv[0] = xr0[k4]; xv[1] = xr1[k4]; xv[2] = xr2[k4]; xv[3] = xr3[k4];
#pragma unroll
    for (int kk = 0; kk < 4; kk++) {
      float4 w0 = wl[(k4 * 4 + kk) * 4 + 0];
      float4 w1 = wl[(k4 * 4 + kk) * 4 + 1];
      float4 w2 = wl[(k4 * 4 + kk) * 4 + 2];
      float4 w3 = wl[(k4 * 4 + kk) * 4 + 3];
#pragma unroll
      for (int r = 0; r < 4; r++) {
        float xs = kk == 0 ? xv[r].x : kk == 1 ? xv[r].y : kk == 2 ? xv[r].z : xv[r].w;
        fma4(acc[r][0], xs, w0);
        fma4(acc[r][1], xs, w1);
        fma4(acc[r][2], xs, w2);
        fma4(acc[r][3], xs, w3);
      }
    }
  }
#pragma unroll
  for (int r = 0; r < 4; r++) {
    float dd = dinv[row0 + r];
    float4 a0 = acc[r][0], a1 = acc[r][1], a2 = acc[r][2], a3 = acc[r][3];
    uint4 o0, o1;
    o0.x = pk2(dd * a0.x, dd * a0.y);
    o0.y = pk2(dd * a0.z, dd * a0.w);
    o0.z = pk2(dd * a1.x, dd * a1.y);
    o0.w = pk2(dd * a1.z, dd * a1.w);
    o1.x = pk2(dd * a2.x, dd * a2.y);
    o1.y = pk2(dd * a2.z, dd * a2.w);
    o1.z = pk2(dd * a3.x, dd * a3.y);
    o1.w = pk2(dd * a3.z, dd * a3.w);
    uint4* orow = (uint4*)(tab1 + (size_t)(row0 + r) * 8);
    orow[0] = o0;
    orow[1] = o1;
  }
}

// ==================== agg1 (+bias+ReLU) fused with lin2; 8 lanes per dst ====================
__global__ __launch_bounds__(256) void k_agg1(const unsigned* __restrict__ tab1,
                                              const int* __restrict__ row_start,
                                              const int* __restrict__ row_end,
                                              const int* __restrict__ col,
                                              const float* __restrict__ dinv,
                                              const float* __restrict__ b1,
                                              const float* __restrict__ W2g,
                                              unsigned* __restrict__ tab2) {
  __shared__ float w2[F1][F2];
  __shared__ float b1l[F1];
  int t = threadIdx.x;
  if (t < F1 * F2) w2[t / F2][t % F2] = W2g[t];
  if (t < F1) b1l[t] = b1[t];
  __syncthreads();
  int g = blockIdx.x * 256 + t;
  int d = g >> 3, o = g & 7;
  int q2 = o >> 2, q = o & 3;
  if (d >= NN) return;
  const uint2* T = (const uint2*)tab1;
  float a0 = 0.f, a1 = 0.f, a2 = 0.f, a3 = 0.f;
  auto addrow = [&](int s) {
    uint2 v = T[(size_t)s * 4 + q];
    float2 f0 = up2(v.x), f1 = up2(v.y);
    a0 += f0.x; a1 += f0.y; a2 += f1.x; a3 += f1.y;
  };
  if (q2 == 0) addrow(d);  // self-loop
  int e = row_start[d] + q2, e1 = row_end[d];
  for (; e + 6 < e1; e += 8) {
    int s0 = __builtin_nontemporal_load(col + e);
    int s1 = __builtin_nontemporal_load(col + e + 2);
    int s2 = __builtin_nontemporal_load(col + e + 4);
    int s3 = __builtin_nontemporal_load(col + e + 6);
    addrow(s0); addrow(s1); addrow(s2); addrow(s3);
  }
  for (; e < e1; e += 2) addrow(__builtin_nontemporal_load(col + e));
  a0 += __shfl_xor(a0, 4);
  a1 += __shfl_xor(a1, 4);
  a2 += __shfl_xor(a2, 4);
  a3 += __shfl_xor(a3, 4);
  float dd = dinv[d];
  float h[4];
  h[0] = fmaxf(fmaf(dd, a0, b1l[q * 4 + 0]), 0.f);
  h[1] = fmaxf(fmaf(dd, a1, b1l[q * 4 + 1]), 0.f);
  h[2] = fmaxf(fmaf(dd, a2, b1l[q * 4 + 2]), 0.f);
  h[3] = fmaxf(fmaf(dd, a3, b1l[q * 4 + 3]), 0.f);
  float p[F2];
#pragma unroll
  for (int j = 0; j < F2; j++) {
    float s = 0.f;
#pragma unroll
    for (int kk = 0; kk < 4; kk++) s = fmaf(h[kk], w2[q * 4 + kk][j], s);
    p[j] = s;
  }
#pragma unroll
  for (int j = 0; j < F2; j++) p[j] += __shfl_xor(p[j], 1);
#pragma unroll
  for (int j = 0; j < F2; j++) p[j] += __shfl_xor(p[j], 2);
  if (q2 != 0) return;
  uint2* O = (uint2*)tab2;
  uint2 ov;
  if (q == 0) {
    ov.x = pk2(dd * p[0], dd * p[1]); ov.y = pk2(dd * p[2], dd * p[3]);
  } else if (q == 1) {
    ov.x = pk2(dd * p[4], dd * p[5]); ov.y = pk2(dd * p[6], dd * p[7]);
  } else if (q == 2) {
    ov.x = pk2(dd * p[8], dd * p[9]); ov.y = 0u;
  } else {
    ov.x = 0u; ov.y = 0u;
  }
  O[(size_t)d * 4 + q] = ov;
}

// ==================== agg2 + bias + log_softmax; 8 lanes per dst ====================
__global__ __launch_bounds__(256) void k_agg2(const unsigned* __restrict__ tab2,
                                              const int* __restrict__ row_start,
                                              const int* __restrict__ row_end,
                                              const int* __restrict__ col,
                                              const float* __restrict__ dinv,
                                              const float* __restrict__ b2,
                                              float* __restrict__ out) {
  __shared__ float b2l[F1];  // padded; entries >= F2 are -1e30
  int t = threadIdx.x;
  if (t < F1) b2l[t] = (t < F2) ? b2[t] : -1e30f;
  __syncthreads();
  int g = blockIdx.x * 256 + t;
  int d = g >> 3, o = g & 7;
  int q2 = o >> 2, q = o & 3;
  if (d >= NN) return;
  const uint2* T = (const uint2*)tab2;
  float a0 = 0.f, a1 = 0.f, a2 = 0.f, a3 = 0.f;
  auto addrow = [&](int s) {
    uint2 v = T[(size_t)s * 4 + q];
    float2 f0 = up2(v.x), f1 = up2(v.y);
    a0 += f0.x; a1 += f0.y; a2 += f1.x; a3 += f1.y;
  };
  if (q2 == 0) addrow(d);  // self-loop
  int e = row_start[d] + q2, e1 = row_end[d];
  for (; e + 6 < e1; e += 8) {
    int s0 = __builtin_nontemporal_load(col + e);
    int s1 = __builtin_nontemporal_load(col + e + 2);
    int s2 = __builtin_nontemporal_load(col + e + 4);
    int s3 = __builtin_nontemporal_load(col + e + 6);
    addrow(s0); addrow(s1); addrow(s2); addrow(s3);
  }
  for (; e < e1; e += 2) addrow(__builtin_nontemporal_load(col + e));
  a0 += __shfl_xor(a0, 4);
  a1 += __shfl_xor(a1, 4);
  a2 += __shfl_xor(a2, 4);
  a3 += __shfl_xor(a3, 4);
  float dd = dinv[d];
  float v0 = fmaf(dd, a0, b2l[q * 4 + 0]);
  float v1 = fmaf(dd, a1, b2l[q * 4 + 1]);
  float v2 = fmaf(dd, a2, b2l[q * 4 + 2]);
  float v3 = fmaf(dd, a3, b2l[q * 4 + 3]);
  float m = fmaxf(fmaxf(v0, v1), fmaxf(v2, v3));
  m = fmaxf(m, __shfl_xor(m, 1));
  m = fmaxf(m, __shfl_xor(m, 2));
  float sum = expf(v0 - m) + expf(v1 - m) + expf(v2 - m) + expf(v3 - m);
  sum += __shfl_xor(sum, 1);
  sum += __shfl_xor(sum, 2);
  float lse = m + logf(sum);
  if (q2 != 0) return;
  float* op = out + (size_t)d * F2;
  if (q == 0) {
    nt_store_f2(v0 - lse, v1 - lse, op + 0);
    nt_store_f2(v2 - lse, v3 - lse, op + 2);
  } else if (q == 1) {
    nt_store_f2(v0 - lse, v1 - lse, op + 4);
    nt_store_f2(v2 - lse, v3 - lse, op + 6);
  } else if (q == 2) {
    nt_store_f2(v0 - lse, v1 - lse, op + 8);
  }
}

extern "C" void kernel_launch(void* const* d_in, const int* in_sizes, int n_in,
                              void* d_out, int out_size, void* d_ws, size_t ws_size,
                              hipStream_t stream) {
  const float* x  = (const float*)d_in[0];
  const int*   ei = (const int*)d_in[1];
  const float* W1 = (const float*)d_in[2];
  const float* b1 = (const float*)d_in[3];
  const float* W2 = (const float*)d_in[4];
  const float* b2 = (const float*)d_in[5];
  float* out = (float*)d_out;
  int E = in_sizes[1] / 2;
  const int* src = ei;
  const int* dst = ei + E;

  char* p = (char*)d_ws;
  auto alloc = [&](size_t bytes) {
    char* r = p;
    p += (bytes + 255) & ~(size_t)255;
    return r;
  };
  size_t tabsz = (size_t)NN * 8 * 4;            // 3.2 MB
  size_t padded = (size_t)NBUCK * MAXB * 4;     // 16.0 MB
  float* dinv       = (float*)alloc((size_t)NN * 4);
  int*   row_start  = (int*)alloc((size_t)NN * 4);
  int*   row_end    = (int*)alloc((size_t)NN * 4);
  int*   bucket_cur = (int*)alloc((size_t)NBUCK * 4);
  int*   col        = (int*)alloc(padded);
  // region A: packed (padded, 16 MB) dead after k_bucket; tab1+tab2 (6.4 MB) overlay it.
  size_t needA = tabsz * 2 > padded ? tabsz * 2 : padded;
  char*  A = (char*)alloc(needA);
  int*      packed = (int*)A;
  unsigned* tab1 = (unsigned*)A;
  unsigned* tab2 = (unsigned*)(A + tabsz);

  int nblk8N = (8 * NN + 255) / 256;     // 3125
  int nblk_place = (E + TILE - 1) / TILE;
  hipLaunchKernelGGL(k_zero, dim3(2), dim3(256), 0, stream, bucket_cur);
  hipLaunchKernelGGL(k_binplace, dim3(nblk_place), dim3(BPT), 0, stream, src, dst, E, bucket_cur, packed);
  hipLaunchKernelGGL(k_bucket, dim3(NBUCK), dim3(256), 0, stream,
                     packed, bucket_cur, row_start, row_end, dinv, col);
  hipLaunchKernelGGL(k_lin1, dim3((NN / 4 + 255) / 256), dim3(256), 0, stream, x, W1, dinv, tab1);
  hipLaunchKernelGGL(k_agg1, dim3(nblk8N), dim3(256), 0, stream,
                     tab1, row_start, row_end, col, dinv, b1, W2, tab2);
  hipLaunchKernelGGL(k_agg2, dim3(nblk8N), dim3(256), 0, stream,
                     tab2, row_start, row_end, col, dinv, b2, out);
}

// Round 13
// 163.975 us; speedup vs baseline: 1.2249x; 1.0473x over previous
//
#include <hip/hip_runtime.h>
#include <hip/hip_fp16.h>
#include <math.h>

#define NN 100000
#define F0 128
#define F1 16
#define F2 10
#define NBUCK 391    // ceil(NN / 256); bucket b covers dsts [b*256, b*256+255]
#define MAXB 10240   // fixed per-bucket capacity (mean 8184 -> 22 sigma slack)
#define TILE 4096    // edges per binplace block -> 782 blocks (~3/CU, balanced)
#define EPT 8        // edges per thread in binplace (TILE / BPT)
#define CAP 10240    // LDS staging capacity in k_bucket (== MAXB)
#define BPT 512      // binplace threads
#define L1R 64       // rows per lin1 block

__device__ inline unsigned pk2(float a, float b) {
  __half ha = __float2half(a), hb = __float2half(b);
  return (unsigned)__half_as_ushort(ha) | ((unsigned)__half_as_ushort(hb) << 16);
}

__device__ inline float2 up2(unsigned u) {
  __half2 h;
  *(unsigned*)&h = u;
  return __half22float2(h);
}

__device__ inline void nt_store_f2(float a, float b, float* p) {
  union { double d; float f[2]; } u;
  u.f[0] = a; u.f[1] = b;
  __builtin_nontemporal_store(u.d, (double*)p);
}

// ==================== CSR build ====================
__global__ void k_zero(int* __restrict__ bucket_cur) {
  int i = blockIdx.x * blockDim.x + threadIdx.x;
  if (i < NBUCK) bucket_cur[i] = 0;
}

// LDS-reorder binplace with remembered-position scatter into fixed-capacity buckets.
__global__ __launch_bounds__(BPT) void k_binplace(const int* __restrict__ src,
                                                  const int* __restrict__ dst, int E,
                                                  int* __restrict__ bucket_cur,
                                                  int* __restrict__ packed) {
  __shared__ int cnt[NBUCK];
  __shared__ int loff[NBUCK];
  __shared__ int gbase[NBUCK];
  __shared__ int part[256];
  __shared__ int stage[TILE];
  int t = threadIdx.x;
  int e0 = blockIdx.x * TILE, e1 = min(E, e0 + TILE);
  int total = e1 - e0;
  for (int i = t; i < NBUCK; i += BPT) cnt[i] = 0;
  __syncthreads();
  // phase A: histogram with remembered positions (pos < 4096 -> 12 bits; bk < 391 -> 9 bits)
  int bkpos[EPT];
  int pval[EPT];
#pragma unroll
  for (int k = 0; k < EPT; k++) {
    int e = e0 + t + k * BPT;
    if (e < e1) {
      int d = __builtin_nontemporal_load(dst + e);
      int s = __builtin_nontemporal_load(src + e);
      int bk = d >> 8;
      int pos = atomicAdd(&cnt[bk], 1);
      bkpos[k] = (bk << 12) | pos;
      pval[k] = (s << 8) | (d & 255);
    } else {
      bkpos[k] = -1;
    }
  }
  __syncthreads();
  // reserve space in fixed-capacity bucket regions
  for (int i = t; i < NBUCK; i += BPT) {
    int c = cnt[i];
    gbase[i] = c ? atomicAdd(&bucket_cur[i], c) : 0;
  }
  // block scan of cnt -> loff
  if (t < 256) {
    int i0 = 2 * t, i1 = 2 * t + 1;
    int c0 = (i0 < NBUCK) ? cnt[i0] : 0;
    int c1 = (i1 < NBUCK) ? cnt[i1] : 0;
    part[t] = c0 + c1;
  }
  __syncthreads();
  for (int o = 1; o < 256; o <<= 1) {
    int add = 0;
    if (t < 256 && t >= o) add = part[t - o];
    __syncthreads();
    if (t < 256) part[t] += add;
    __syncthreads();
  }
  if (t < 256) {
    int i0 = 2 * t, i1 = 2 * t + 1;
    int c0 = (i0 < NBUCK) ? cnt[i0] : 0;
    int c1 = (i1 < NBUCK) ? cnt[i1] : 0;
    int excl = part[t] - c0 - c1;
    if (i0 < NBUCK) loff[i0] = excl;
    if (i1 < NBUCK) loff[i1] = excl + c0;
  }
  __syncthreads();
  // phase B: atomic-free LDS scatter
#pragma unroll
  for (int k = 0; k < EPT; k++) {
    if (bkpos[k] >= 0) {
      int bk = bkpos[k] >> 12, pos = bkpos[k] & 4095;
      stage[loff[bk] + pos] = pval[k];
    }
  }
  __syncthreads();
  // contiguous run copy into padded bucket regions
  int sub = t >> 4, lane = t & 15;
  for (int bk = sub; bk < NBUCK; bk += BPT / 16) {
    int lo = loff[bk];
    int hi = (bk + 1 < NBUCK) ? loff[bk + 1] : total;
    size_t gb = (size_t)bk * MAXB + gbase[bk];
    for (int i = lo + lane; i < hi; i += 16) packed[gb + (i - lo)] = stage[i];
  }
}

// fine pass: remembered-position histogram (1 LDS atomic/edge), scan, atomic-free col write.
__global__ __launch_bounds__(256) void k_bucket(const int* __restrict__ packed,
                                                const int* __restrict__ bucket_cur,
                                                int* __restrict__ row_start,
                                                int* __restrict__ row_end,
                                                float* __restrict__ dinv,
                                                int* __restrict__ col) {
  __shared__ int stage[CAP];
  __shared__ unsigned short posa[CAP];
  __shared__ int hist[256];
  __shared__ int offx[256];
  __shared__ int scan[256];
  __shared__ int cur[256];
  int b = blockIdx.x, t = threadIdx.x;
  size_t base = (size_t)b * MAXB;
  int cnt_b = bucket_cur[b];
  hist[t] = 0;
  __syncthreads();
  bool staged = (cnt_b <= CAP);  // always true in practice
  if (staged) {
    for (int i = t; i < cnt_b; i += 256) {
      int p = __builtin_nontemporal_load(packed + base + i);
      stage[i] = p;
      int pos = atomicAdd(&hist[p & 255], 1);
      posa[i] = (unsigned short)pos;
    }
  } else {
    for (int i = t; i < cnt_b; i += 256)
      atomicAdd(&hist[packed[base + i] & 255], 1);
  }
  __syncthreads();
  int v = hist[t];
  scan[t] = v;
  __syncthreads();
  for (int o = 1; o < 256; o <<= 1) {
    int add = (t >= o) ? scan[t - o] : 0;
    __syncthreads();
    scan[t] += add;
    __syncthreads();
  }
  int excl = scan[t] - v;
  offx[t] = excl;
  cur[t] = excl;
  int d = b * 256 + t;
  if (d < NN) {
    row_start[d] = (int)base + excl;
    row_end[d] = (int)base + excl + v;
    dinv[d] = rsqrtf((float)(v + 1));  // +1 self-loop
  }
  __syncthreads();
  if (staged) {
    for (int i = t; i < cnt_b; i += 256) {
      int p = stage[i];
      col[base + offx[p & 255] + posa[i]] = p >> 8;
    }
  } else {
    for (int i = t; i < cnt_b; i += 256) {
      int p = packed[base + i];
      int pos = atomicAdd(&cur[p & 255], 1);
      col[base + pos] = p >> 8;
    }
  }
}

// ==================== tab1 = fp16(dinv * (x @ W1)) ====================
// LDS-tiled: 64 rows/block (1563 blocks), coalesced x staging (pad stride 33 to
// avoid 16-way bank conflict), thread = (row, feature-quad), coalesced uint2 out.
__global__ __launch_bounds__(256) void k_lin1(const float* __restrict__ x,
                                              const float* __restrict__ W1,
                                              const float* __restrict__ dinv,
                                              unsigned* __restrict__ tab1) {
  __shared__ float4 wl[F0 * 4];       // [k][jq], 8 KB
  __shared__ float4 xs[L1R * 33];     // 64 rows x 32 float4, stride 33 (33.8 KB)
  int t = threadIdx.x;
  for (int i = t; i < F0 * 4; i += 256) wl[i] = ((const float4*)W1)[i];
  int row0 = blockIdx.x * L1R;
  int nrows = min(L1R, NN - row0);
  const float4* xg = (const float4*)(x + (size_t)row0 * F0);
  for (int i = t; i < nrows * 32; i += 256) {
    int rr = i >> 5, cc = i & 31;
    xs[rr * 33 + cc] = xg[i];
  }
  __syncthreads();
  int r = t >> 2, q = t & 3;
  if (r >= nrows) return;
  int d = row0 + r;
  float4 acc = make_float4(0.f, 0.f, 0.f, 0.f);
#pragma unroll
  for (int k4 = 0; k4 < 32; k4++) {
    float4 xv = xs[r * 33 + k4];
    float4 w0 = wl[(k4 * 4 + 0) * 4 + q];
    float4 w1 = wl[(k4 * 4 + 1) * 4 + q];
    float4 w2 = wl[(k4 * 4 + 2) * 4 + q];
    float4 w3 = wl[(k4 * 4 + 3) * 4 + q];
    acc.x = fmaf(xv.x, w0.x, fmaf(xv.y, w1.x, fmaf(xv.z, w2.x, fmaf(xv.w, w3.x, acc.x))));
    acc.y = fmaf(xv.x, w0.y, fmaf(xv.y, w1.y, fmaf(xv.z, w2.y, fmaf(xv.w, w3.y, acc.y))));
    acc.z = fmaf(xv.x, w0.z, fmaf(xv.y, w1.z, fmaf(xv.z, w2.z, fmaf(xv.w, w3.z, acc.z))));
    acc.w = fmaf(xv.x, w0.w, fmaf(xv.y, w1.w, fmaf(xv.z, w2.w, fmaf(xv.w, w3.w, acc.w))));
  }
  float dd = dinv[d];
  uint2 o;
  o.x = pk2(dd * acc.x, dd * acc.y);
  o.y = pk2(dd * acc.z, dd * acc.w);
  ((uint2*)tab1)[(size_t)d * 4 + q] = o;
}

// ==================== agg1 (+bias+ReLU) fused with lin2; 8 lanes per dst ====================
__global__ __launch_bounds__(256) void k_agg1(const unsigned* __restrict__ tab1,
                                              const int* __restrict__ row_start,
                                              const int* __restrict__ row_end,
                                              const int* __restrict__ col,
                                              const float* __restrict__ dinv,
                                              const float* __restrict__ b1,
                                              const float* __restrict__ W2g,
                                              unsigned* __restrict__ tab2) {
  __shared__ float w2[F1][F2];
  __shared__ float b1l[F1];
  int t = threadIdx.x;
  if (t < F1 * F2) w2[t / F2][t % F2] = W2g[t];
  if (t < F1) b1l[t] = b1[t];
  __syncthreads();
  int g = blockIdx.x * 256 + t;
  int d = g >> 3, o = g & 7;
  int q2 = o >> 2, q = o & 3;
  if (d >= NN) return;
  const uint2* T = (const uint2*)tab1;
  float a0 = 0.f, a1 = 0.f, a2 = 0.f, a3 = 0.f;
  auto addrow = [&](int s) {
    uint2 v = T[(size_t)s * 4 + q];
    float2 f0 = up2(v.x), f1 = up2(v.y);
    a0 += f0.x; a1 += f0.y; a2 += f1.x; a3 += f1.y;
  };
  if (q2 == 0) addrow(d);  // self-loop
  int e = row_start[d] + q2, e1 = row_end[d];
  for (; e + 6 < e1; e += 8) {
    int s0 = __builtin_nontemporal_load(col + e);
    int s1 = __builtin_nontemporal_load(col + e + 2);
    int s2 = __builtin_nontemporal_load(col + e + 4);
    int s3 = __builtin_nontemporal_load(col + e + 6);
    addrow(s0); addrow(s1); addrow(s2); addrow(s3);
  }
  for (; e < e1; e += 2) addrow(__builtin_nontemporal_load(col + e));
  a0 += __shfl_xor(a0, 4);
  a1 += __shfl_xor(a1, 4);
  a2 += __shfl_xor(a2, 4);
  a3 += __shfl_xor(a3, 4);
  float dd = dinv[d];
  float h[4];
  h[0] = fmaxf(fmaf(dd, a0, b1l[q * 4 + 0]), 0.f);
  h[1] = fmaxf(fmaf(dd, a1, b1l[q * 4 + 1]), 0.f);
  h[2] = fmaxf(fmaf(dd, a2, b1l[q * 4 + 2]), 0.f);
  h[3] = fmaxf(fmaf(dd, a3, b1l[q * 4 + 3]), 0.f);
  float p[F2];
#pragma unroll
  for (int j = 0; j < F2; j++) {
    float s = 0.f;
#pragma unroll
    for (int kk = 0; kk < 4; kk++) s = fmaf(h[kk], w2[q * 4 + kk][j], s);
    p[j] = s;
  }
#pragma unroll
  for (int j = 0; j < F2; j++) p[j] += __shfl_xor(p[j], 1);
#pragma unroll
  for (int j = 0; j < F2; j++) p[j] += __shfl_xor(p[j], 2);
  if (q2 != 0) return;
  uint2* O = (uint2*)tab2;
  uint2 ov;
  if (q == 0) {
    ov.x = pk2(dd * p[0], dd * p[1]); ov.y = pk2(dd * p[2], dd * p[3]);
  } else if (q == 1) {
    ov.x = pk2(dd * p[4], dd * p[5]); ov.y = pk2(dd * p[6], dd * p[7]);
  } else if (q == 2) {
    ov.x = pk2(dd * p[8], dd * p[9]); ov.y = 0u;
  } else {
    ov.x = 0u; ov.y = 0u;
  }
  O[(size_t)d * 4 + q] = ov;
}

// ==================== agg2 + bias + log_softmax; 8 lanes per dst ====================
__global__ __launch_bounds__(256) void k_agg2(const unsigned* __restrict__ tab2,
                                              const int* __restrict__ row_start,
                                              const int* __restrict__ row_end,
                                              const int* __restrict__ col,
                                              const float* __restrict__ dinv,
                                              const float* __restrict__ b2,
                                              float* __restrict__ out) {
  __shared__ float b2l[F1];  // padded; entries >= F2 are -1e30
  int t = threadIdx.x;
  if (t < F1) b2l[t] = (t < F2) ? b2[t] : -1e30f;
  __syncthreads();
  int g = blockIdx.x * 256 + t;
  int d = g >> 3, o = g & 7;
  int q2 = o >> 2, q = o & 3;
  if (d >= NN) return;
  const uint2* T = (const uint2*)tab2;
  float a0 = 0.f, a1 = 0.f, a2 = 0.f, a3 = 0.f;
  auto addrow = [&](int s) {
    uint2 v = T[(size_t)s * 4 + q];
    float2 f0 = up2(v.x), f1 = up2(v.y);
    a0 += f0.x; a1 += f0.y; a2 += f1.x; a3 += f1.y;
  };
  if (q2 == 0) addrow(d);  // self-loop
  int e = row_start[d] + q2, e1 = row_end[d];
  for (; e + 6 < e1; e += 8) {
    int s0 = __builtin_nontemporal_load(col + e);
    int s1 = __builtin_nontemporal_load(col + e + 2);
    int s2 = __builtin_nontemporal_load(col + e + 4);
    int s3 = __builtin_nontemporal_load(col + e + 6);
    addrow(s0); addrow(s1); addrow(s2); addrow(s3);
  }
  for (; e < e1; e += 2) addrow(__builtin_nontemporal_load(col + e));
  a0 += __shfl_xor(a0, 4);
  a1 += __shfl_xor(a1, 4);
  a2 += __shfl_xor(a2, 4);
  a3 += __shfl_xor(a3, 4);
  float dd = dinv[d];
  float v0 = fmaf(dd, a0, b2l[q * 4 + 0]);
  float v1 = fmaf(dd, a1, b2l[q * 4 + 1]);
  float v2 = fmaf(dd, a2, b2l[q * 4 + 2]);
  float v3 = fmaf(dd, a3, b2l[q * 4 + 3]);
  float m = fmaxf(fmaxf(v0, v1), fmaxf(v2, v3));
  m = fmaxf(m, __shfl_xor(m, 1));
  m = fmaxf(m, __shfl_xor(m, 2));
  float sum = expf(v0 - m) + expf(v1 - m) + expf(v2 - m) + expf(v3 - m);
  sum += __shfl_xor(sum, 1);
  sum += __shfl_xor(sum, 2);
  float lse = m + logf(sum);
  if (q2 != 0) return;
  float* op = out + (size_t)d * F2;
  if (q == 0) {
    nt_store_f2(v0 - lse, v1 - lse, op + 0);
    nt_store_f2(v2 - lse, v3 - lse, op + 2);
  } else if (q == 1) {
    nt_store_f2(v0 - lse, v1 - lse, op + 4);
    nt_store_f2(v2 - lse, v3 - lse, op + 6);
  } else if (q == 2) {
    nt_store_f2(v0 - lse, v1 - lse, op + 8);
  }
}

extern "C" void kernel_launch(void* const* d_in, const int* in_sizes, int n_in,
                              void* d_out, int out_size, void* d_ws, size_t ws_size,
                              hipStream_t stream) {
  const float* x  = (const float*)d_in[0];
  const int*   ei = (const int*)d_in[1];
  const float* W1 = (const float*)d_in[2];
  const float* b1 = (const float*)d_in[3];
  const float* W2 = (const float*)d_in[4];
  const float* b2 = (const float*)d_in[5];
  float* out = (float*)d_out;
  int E = in_sizes[1] / 2;
  const int* src = ei;
  const int* dst = ei + E;

  char* p = (char*)d_ws;
  auto alloc = [&](size_t bytes) {
    char* r = p;
    p += (bytes + 255) & ~(size_t)255;
    return r;
  };
  size_t tabsz = (size_t)NN * 8 * 4;            // 3.2 MB
  size_t padded = (size_t)NBUCK * MAXB * 4;     // 16.0 MB
  float* dinv       = (float*)alloc((size_t)NN * 4);
  int*   row_start  = (int*)alloc((size_t)NN * 4);
  int*   row_end    = (int*)alloc((size_t)NN * 4);
  int*   bucket_cur = (int*)alloc((size_t)NBUCK * 4);
  int*   col        = (int*)alloc(padded);
  // region A: packed (16 MB) dead after k_bucket; tab1+tab2 (6.4 MB) overlay it.
  size_t needA = tabsz * 2 > padded ? tabsz * 2 : padded;
  char*  A = (char*)alloc(needA);
  int*      packed = (int*)A;
  unsigned* tab1 = (unsigned*)A;
  unsigned* tab2 = (unsigned*)(A + tabsz);

  int nblk8N = (8 * NN + 255) / 256;     // 3125
  int nblk_place = (E + TILE - 1) / TILE;  // 782
  int nblk_lin1 = (NN + L1R - 1) / L1R;    // 1563
  hipLaunchKernelGGL(k_zero, dim3(2), dim3(256), 0, stream, bucket_cur);
  hipLaunchKernelGGL(k_binplace, dim3(nblk_place), dim3(BPT), 0, stream, src, dst, E, bucket_cur, packed);
  hipLaunchKernelGGL(k_bucket, dim3(NBUCK), dim3(256), 0, stream,
                     packed, bucket_cur, row_start, row_end, dinv, col);
  hipLaunchKernelGGL(k_lin1, dim3(nblk_lin1), dim3(256), 0, stream, x, W1, dinv, tab1);
  hipLaunchKernelGGL(k_agg1, dim3(nblk8N), dim3(256), 0, stream,
                     tab1, row_start, row_end, col, dinv, b1, W2, tab2);
  hipLaunchKernelGGL(k_agg2, dim3(nblk8N), dim3(256), 0, stream,
                     tab2, row_start, row_end, col, dinv, b2, out);
}

// Round 14
// 161.302 us; speedup vs baseline: 1.2452x; 1.0166x over previous
//
#include <hip/hip_runtime.h>
#include <hip/hip_fp16.h>
#include <math.h>

#define NN 100000
#define F0 128
#define F1 16
#define F2 10
#define NBUCK 391    // ceil(NN / 256); bucket b covers dsts [b*256, b*256+255]
#define MAXB 10240   // fixed per-bucket capacity (mean 8184 -> 22 sigma slack)
#define TILE 4096    // edges per binplace block -> 782 blocks
#define EPT 8        // edges per thread in binplace (TILE / BPT)
#define CAP 10240    // LDS staging capacity in k_bucket (== MAXB)
#define BPT 512      // binplace threads
#define BKT 512      // bucket threads
#define L1R 64       // rows per lin1 block

__device__ inline unsigned pk2(float a, float b) {
  __half ha = __float2half(a), hb = __float2half(b);
  return (unsigned)__half_as_ushort(ha) | ((unsigned)__half_as_ushort(hb) << 16);
}

__device__ inline float2 up2(unsigned u) {
  __half2 h;
  *(unsigned*)&h = u;
  return __half22float2(h);
}

__device__ inline void nt_store_f2(float a, float b, float* p) {
  union { double d; float f[2]; } u;
  u.f[0] = a; u.f[1] = b;
  __builtin_nontemporal_store(u.d, (double*)p);
}

// ==================== CSR build ====================
__global__ void k_zero(int* __restrict__ bucket_cur) {
  int i = blockIdx.x * blockDim.x + threadIdx.x;
  if (i < NBUCK) bucket_cur[i] = 0;
}

// LDS-reorder binplace with remembered-position scatter into fixed-capacity buckets.
__global__ __launch_bounds__(BPT) void k_binplace(const int* __restrict__ src,
                                                  const int* __restrict__ dst, int E,
                                                  int* __restrict__ bucket_cur,
                                                  int* __restrict__ packed) {
  __shared__ int cnt[NBUCK];
  __shared__ int loff[NBUCK];
  __shared__ int gbase[NBUCK];
  __shared__ int part[256];
  __shared__ int stage[TILE];
  int t = threadIdx.x;
  int e0 = blockIdx.x * TILE, e1 = min(E, e0 + TILE);
  int total = e1 - e0;
  for (int i = t; i < NBUCK; i += BPT) cnt[i] = 0;
  __syncthreads();
  // phase A: histogram with remembered positions (pos < 4096 -> 12 bits)
  int bkpos[EPT];
  int pval[EPT];
#pragma unroll
  for (int k = 0; k < EPT; k++) {
    int e = e0 + t + k * BPT;
    if (e < e1) {
      int d = __builtin_nontemporal_load(dst + e);
      int s = __builtin_nontemporal_load(src + e);
      int bk = d >> 8;
      int pos = atomicAdd(&cnt[bk], 1);
      bkpos[k] = (bk << 12) | pos;
      pval[k] = (s << 8) | (d & 255);
    } else {
      bkpos[k] = -1;
    }
  }
  __syncthreads();
  // reserve space in fixed-capacity bucket regions
  for (int i = t; i < NBUCK; i += BPT) {
    int c = cnt[i];
    gbase[i] = c ? atomicAdd(&bucket_cur[i], c) : 0;
  }
  // block scan of cnt -> loff
  if (t < 256) {
    int i0 = 2 * t, i1 = 2 * t + 1;
    int c0 = (i0 < NBUCK) ? cnt[i0] : 0;
    int c1 = (i1 < NBUCK) ? cnt[i1] : 0;
    part[t] = c0 + c1;
  }
  __syncthreads();
  for (int o = 1; o < 256; o <<= 1) {
    int add = 0;
    if (t < 256 && t >= o) add = part[t - o];
    __syncthreads();
    if (t < 256) part[t] += add;
    __syncthreads();
  }
  if (t < 256) {
    int i0 = 2 * t, i1 = 2 * t + 1;
    int c0 = (i0 < NBUCK) ? cnt[i0] : 0;
    int c1 = (i1 < NBUCK) ? cnt[i1] : 0;
    int excl = part[t] - c0 - c1;
    if (i0 < NBUCK) loff[i0] = excl;
    if (i1 < NBUCK) loff[i1] = excl + c0;
  }
  __syncthreads();
  // phase B: atomic-free LDS scatter
#pragma unroll
  for (int k = 0; k < EPT; k++) {
    if (bkpos[k] >= 0) {
      int bk = bkpos[k] >> 12, pos = bkpos[k] & 4095;
      stage[loff[bk] + pos] = pval[k];
    }
  }
  __syncthreads();
  // contiguous run copy into padded bucket regions
  int sub = t >> 4, lane = t & 15;
  for (int bk = sub; bk < NBUCK; bk += BPT / 16) {
    int lo = loff[bk];
    int hi = (bk + 1 < NBUCK) ? loff[bk + 1] : total;
    size_t gb = (size_t)bk * MAXB + gbase[bk];
    for (int i = lo + lane; i < hi; i += 16) packed[gb + (i - lo)] = stage[i];
  }
}

// fine pass: remembered-position histogram (1 LDS atomic/edge), scan, atomic-free col write.
__global__ __launch_bounds__(BKT) void k_bucket(const int* __restrict__ packed,
                                                const int* __restrict__ bucket_cur,
                                                int* __restrict__ row_start,
                                                int* __restrict__ row_end,
                                                float* __restrict__ dinv,
                                                int* __restrict__ col) {
  __shared__ int stage[CAP];
  __shared__ unsigned short posa[CAP];
  __shared__ int hist[256];
  __shared__ int offx[256];
  __shared__ int scan[256];
  __shared__ int cur[256];
  int b = blockIdx.x, t = threadIdx.x;
  size_t base = (size_t)b * MAXB;
  int cnt_b = bucket_cur[b];
  if (t < 256) hist[t] = 0;
  __syncthreads();
  bool staged = (cnt_b <= CAP);  // always true in practice
  if (staged) {
    for (int i = t; i < cnt_b; i += BKT) {
      int p = __builtin_nontemporal_load(packed + base + i);
      stage[i] = p;
      int pos = atomicAdd(&hist[p & 255], 1);
      posa[i] = (unsigned short)pos;
    }
  } else {
    for (int i = t; i < cnt_b; i += BKT)
      atomicAdd(&hist[packed[base + i] & 255], 1);
  }
  __syncthreads();
  int v = (t < 256) ? hist[t] : 0;
  if (t < 256) scan[t] = v;
  __syncthreads();
  for (int o = 1; o < 256; o <<= 1) {
    int add = 0;
    if (t < 256 && t >= o) add = scan[t - o];
    __syncthreads();
    if (t < 256) scan[t] += add;
    __syncthreads();
  }
  if (t < 256) {
    int excl = scan[t] - v;
    offx[t] = excl;
    cur[t] = excl;
    int d = b * 256 + t;
    if (d < NN) {
      row_start[d] = (int)base + excl;
      row_end[d] = (int)base + excl + v;
      dinv[d] = rsqrtf((float)(v + 1));  // +1 self-loop
    }
  }
  __syncthreads();
  if (staged) {
    for (int i = t; i < cnt_b; i += BKT) {
      int p = stage[i];
      col[base + offx[p & 255] + posa[i]] = p >> 8;
    }
  } else {
    for (int i = t; i < cnt_b; i += BKT) {
      int p = packed[base + i];
      int pos = atomicAdd(&cur[p & 255], 1);
      col[base + pos] = p >> 8;
    }
  }
}

// ==================== tab1 = fp16(dinv * (x @ W1)) ====================
__global__ __launch_bounds__(256) void k_lin1(const float* __restrict__ x,
                                              const float* __restrict__ W1,
                                              const float* __restrict__ dinv,
                                              unsigned* __restrict__ tab1) {
  __shared__ float4 wl[F0 * 4];       // [k][jq], 8 KB
  __shared__ float4 xs[L1R * 33];     // 64 rows x 32 float4, stride 33
  int t = threadIdx.x;
  for (int i = t; i < F0 * 4; i += 256) wl[i] = ((const float4*)W1)[i];
  int row0 = blockIdx.x * L1R;
  int nrows = min(L1R, NN - row0);
  const float4* xg = (const float4*)(x + (size_t)row0 * F0);
  for (int i = t; i < nrows * 32; i += 256) {
    int rr = i >> 5, cc = i & 31;
    xs[rr * 33 + cc] = xg[i];
  }
  __syncthreads();
  int r = t >> 2, q = t & 3;
  if (r >= nrows) return;
  int d = row0 + r;
  float4 acc = make_float4(0.f, 0.f, 0.f, 0.f);
#pragma unroll
  for (int k4 = 0; k4 < 32; k4++) {
    float4 xv = xs[r * 33 + k4];
    float4 w0 = wl[(k4 * 4 + 0) * 4 + q];
    float4 w1 = wl[(k4 * 4 + 1) * 4 + q];
    float4 w2 = wl[(k4 * 4 + 2) * 4 + q];
    float4 w3 = wl[(k4 * 4 + 3) * 4 + q];
    acc.x = fmaf(xv.x, w0.x, fmaf(xv.y, w1.x, fmaf(xv.z, w2.x, fmaf(xv.w, w3.x, acc.x))));
    acc.y = fmaf(xv.x, w0.y, fmaf(xv.y, w1.y, fmaf(xv.z, w2.y, fmaf(xv.w, w3.y, acc.y))));
    acc.z = fmaf(xv.x, w0.z, fmaf(xv.y, w1.z, fmaf(xv.z, w2.z, fmaf(xv.w, w3.z, acc.z))));
    acc.w = fmaf(xv.x, w0.w, fmaf(xv.y, w1.w, fmaf(xv.z, w2.w, fmaf(xv.w, w3.w, acc.w))));
  }
  float dd = dinv[d];
  uint2 o;
  o.x = pk2(dd * acc.x, dd * acc.y);
  o.y = pk2(dd * acc.z, dd * acc.w);
  ((uint2*)tab1)[(size_t)d * 4 + q] = o;
}

// ==================== agg1 (+bias+ReLU) fused with lin2; 8 lanes per dst ====================
// Batch-8 gather loop: 8 col loads -> 8 independent row loads -> accumulate (deep ILP).
__global__ __launch_bounds__(256) void k_agg1(const unsigned* __restrict__ tab1,
                                              const int* __restrict__ row_start,
                                              const int* __restrict__ row_end,
                                              const int* __restrict__ col,
                                              const float* __restrict__ dinv,
                                              const float* __restrict__ b1,
                                              const float* __restrict__ W2g,
                                              unsigned* __restrict__ tab2) {
  __shared__ float w2[F1][F2];
  __shared__ float b1l[F1];
  int t = threadIdx.x;
  if (t < F1 * F2) w2[t / F2][t % F2] = W2g[t];
  if (t < F1) b1l[t] = b1[t];
  __syncthreads();
  int g = blockIdx.x * 256 + t;
  int d = g >> 3, o = g & 7;
  int q2 = o >> 2, q = o & 3;
  if (d >= NN) return;
  const uint2* T = (const uint2*)tab1;
  float a0 = 0.f, a1 = 0.f, a2 = 0.f, a3 = 0.f;
  auto acc8 = [&](uint2 v) {
    float2 f0 = up2(v.x), f1 = up2(v.y);
    a0 += f0.x; a1 += f0.y; a2 += f1.x; a3 += f1.y;
  };
  if (q2 == 0) acc8(T[(size_t)d * 4 + q]);  // self-loop
  int e = row_start[d] + q2, e1 = row_end[d];
  for (; e + 14 < e1; e += 16) {
    int s[8];
#pragma unroll
    for (int k = 0; k < 8; k++) s[k] = __builtin_nontemporal_load(col + e + 2 * k);
    uint2 vv[8];
#pragma unroll
    for (int k = 0; k < 8; k++) vv[k] = T[(size_t)s[k] * 4 + q];
#pragma unroll
    for (int k = 0; k < 8; k++) acc8(vv[k]);
  }
  for (; e < e1; e += 2) acc8(T[(size_t)__builtin_nontemporal_load(col + e) * 4 + q]);
  a0 += __shfl_xor(a0, 4);
  a1 += __shfl_xor(a1, 4);
  a2 += __shfl_xor(a2, 4);
  a3 += __shfl_xor(a3, 4);
  float dd = dinv[d];
  float h[4];
  h[0] = fmaxf(fmaf(dd, a0, b1l[q * 4 + 0]), 0.f);
  h[1] = fmaxf(fmaf(dd, a1, b1l[q * 4 + 1]), 0.f);
  h[2] = fmaxf(fmaf(dd, a2, b1l[q * 4 + 2]), 0.f);
  h[3] = fmaxf(fmaf(dd, a3, b1l[q * 4 + 3]), 0.f);
  float p[F2];
#pragma unroll
  for (int j = 0; j < F2; j++) {
    float s = 0.f;
#pragma unroll
    for (int kk = 0; kk < 4; kk++) s = fmaf(h[kk], w2[q * 4 + kk][j], s);
    p[j] = s;
  }
#pragma unroll
  for (int j = 0; j < F2; j++) p[j] += __shfl_xor(p[j], 1);
#pragma unroll
  for (int j = 0; j < F2; j++) p[j] += __shfl_xor(p[j], 2);
  if (q2 != 0) return;
  uint2* O = (uint2*)tab2;
  uint2 ov;
  if (q == 0) {
    ov.x = pk2(dd * p[0], dd * p[1]); ov.y = pk2(dd * p[2], dd * p[3]);
  } else if (q == 1) {
    ov.x = pk2(dd * p[4], dd * p[5]); ov.y = pk2(dd * p[6], dd * p[7]);
  } else if (q == 2) {
    ov.x = pk2(dd * p[8], dd * p[9]); ov.y = 0u;
  } else {
    ov.x = 0u; ov.y = 0u;
  }
  O[(size_t)d * 4 + q] = ov;
}

// ==================== agg2 + bias + log_softmax; 8 lanes per dst ====================
__global__ __launch_bounds__(256) void k_agg2(const unsigned* __restrict__ tab2,
                                              const int* __restrict__ row_start,
                                              const int* __restrict__ row_end,
                                              const int* __restrict__ col,
                                              const float* __restrict__ dinv,
                                              const float* __restrict__ b2,
                                              float* __restrict__ out) {
  __shared__ float b2l[F1];  // padded; entries >= F2 are -1e30
  int t = threadIdx.x;
  if (t < F1) b2l[t] = (t < F2) ? b2[t] : -1e30f;
  __syncthreads();
  int g = blockIdx.x * 256 + t;
  int d = g >> 3, o = g & 7;
  int q2 = o >> 2, q = o & 3;
  if (d >= NN) return;
  const uint2* T = (const uint2*)tab2;
  float a0 = 0.f, a1 = 0.f, a2 = 0.f, a3 = 0.f;
  auto acc8 = [&](uint2 v) {
    float2 f0 = up2(v.x), f1 = up2(v.y);
    a0 += f0.x; a1 += f0.y; a2 += f1.x; a3 += f1.y;
  };
  if (q2 == 0) acc8(T[(size_t)d * 4 + q]);  // self-loop
  int e = row_start[d] + q2, e1 = row_end[d];
  for (; e + 14 < e1; e += 16) {
    int s[8];
#pragma unroll
    for (int k = 0; k < 8; k++) s[k] = __builtin_nontemporal_load(col + e + 2 * k);
    uint2 vv[8];
#pragma unroll
    for (int k = 0; k < 8; k++) vv[k] = T[(size_t)s[k] * 4 + q];
#pragma unroll
    for (int k = 0; k < 8; k++) acc8(vv[k]);
  }
  for (; e < e1; e += 2) acc8(T[(size_t)__builtin_nontemporal_load(col + e) * 4 + q]);
  a0 += __shfl_xor(a0, 4);
  a1 += __shfl_xor(a1, 4);
  a2 += __shfl_xor(a2, 4);
  a3 += __shfl_xor(a3, 4);
  float dd = dinv[d];
  float v0 = fmaf(dd, a0, b2l[q * 4 + 0]);
  float v1 = fmaf(dd, a1, b2l[q * 4 + 1]);
  float v2 = fmaf(dd, a2, b2l[q * 4 + 2]);
  float v3 = fmaf(dd, a3, b2l[q * 4 + 3]);
  float m = fmaxf(fmaxf(v0, v1), fmaxf(v2, v3));
  m = fmaxf(m, __shfl_xor(m, 1));
  m = fmaxf(m, __shfl_xor(m, 2));
  float sum = expf(v0 - m) + expf(v1 - m) + expf(v2 - m) + expf(v3 - m);
  sum += __shfl_xor(sum, 1);
  sum += __shfl_xor(sum, 2);
  float lse = m + logf(sum);
  if (q2 != 0) return;
  float* op = out + (size_t)d * F2;
  if (q == 0) {
    nt_store_f2(v0 - lse, v1 - lse, op + 0);
    nt_store_f2(v2 - lse, v3 - lse, op + 2);
  } else if (q == 1) {
    nt_store_f2(v0 - lse, v1 - lse, op + 4);
    nt_store_f2(v2 - lse, v3 - lse, op + 6);
  } else if (q == 2) {
    nt_store_f2(v0 - lse, v1 - lse, op + 8);
  }
}

extern "C" void kernel_launch(void* const* d_in, const int* in_sizes, int n_in,
                              void* d_out, int out_size, void* d_ws, size_t ws_size,
                              hipStream_t stream) {
  const float* x  = (const float*)d_in[0];
  const int*   ei = (const int*)d_in[1];
  const float* W1 = (const float*)d_in[2];
  const float* b1 = (const float*)d_in[3];
  const float* W2 = (const float*)d_in[4];
  const float* b2 = (const float*)d_in[5];
  float* out = (float*)d_out;
  int E = in_sizes[1] / 2;
  const int* src = ei;
  const int* dst = ei + E;

  char* p = (char*)d_ws;
  auto alloc = [&](size_t bytes) {
    char* r = p;
    p += (bytes + 255) & ~(size_t)255;
    return r;
  };
  size_t tabsz = (size_t)NN * 8 * 4;            // 3.2 MB
  size_t padded = (size_t)NBUCK * MAXB * 4;     // 16.0 MB
  float* dinv       = (float*)alloc((size_t)NN * 4);
  int*   row_start  = (int*)alloc((size_t)NN * 4);
  int*   row_end    = (int*)alloc((size_t)NN * 4);
  int*   bucket_cur = (int*)alloc((size_t)NBUCK * 4);
  int*   col        = (int*)alloc(padded);
  size_t needA = tabsz * 2 > padded ? tabsz * 2 : padded;
  char*  A = (char*)alloc(needA);
  int*      packed = (int*)A;
  unsigned* tab1 = (unsigned*)A;
  unsigned* tab2 = (unsigned*)(A + tabsz);

  int nblk8N = (8 * NN + 255) / 256;       // 3125
  int nblk_place = (E + TILE - 1) / TILE;  // 782
  int nblk_lin1 = (NN + L1R - 1) / L1R;    // 1563
  hipLaunchKernelGGL(k_zero, dim3(2), dim3(256), 0, stream, bucket_cur);
  hipLaunchKernelGGL(k_binplace, dim3(nblk_place), dim3(BPT), 0, stream, src, dst, E, bucket_cur, packed);
  hipLaunchKernelGGL(k_bucket, dim3(NBUCK), dim3(BKT), 0, stream,
                     packed, bucket_cur, row_start, row_end, dinv, col);
  hipLaunchKernelGGL(k_lin1, dim3(nblk_lin1), dim3(256), 0, stream, x, W1, dinv, tab1);
  hipLaunchKernelGGL(k_agg1, dim3(nblk8N), dim3(256), 0, stream,
                     tab1, row_start, row_end, col, dinv, b1, W2, tab2);
  hipLaunchKernelGGL(k_agg2, dim3(nblk8N), dim3(256), 0, stream,
                     tab2, row_start, row_end, col, dinv, b2, out);
}